// Round 5
// baseline (804.782 us; speedup 1.0000x reference)
//
#include <hip/hip_runtime.h>
#include <cstdint>
#include <cstddef>

// ---------------- dims ----------------
#define BATCH 2
#define MQ 12544          // B * TQ * NQ
#define ROWS_Q 6272
#define MK 4096           // B * T*H*W
#define ROWS_K 2048
#define HID 512
#define NH 4
#define HD 128
#define EMB 1024
#define DQ 896
#define FF 1024
#define OUTD 896

typedef __bf16 bf16;
typedef unsigned int u32;
typedef bf16 bf16x8 __attribute__((ext_vector_type(8)));
typedef bf16 bf16x4 __attribute__((ext_vector_type(4)));
typedef float f32x4 __attribute__((ext_vector_type(4)));

enum { OP_BIAS = 0, OP_GELU = 1, OP_RES = 2 };

__device__ __forceinline__ float gelu_tanh(float x) {
    float x3 = x * x * x;
    return 0.5f * x * (1.0f + tanhf(0.7978845608028654f * (x + 0.044715f * x3)));
}

__device__ __forceinline__ void gld16(const bf16* g, bf16* l) {
    __builtin_amdgcn_global_load_lds(
        (const __attribute__((address_space(1))) unsigned int*)g,
        (__attribute__((address_space(3))) unsigned int*)l, 16, 0, 0);
}

__device__ __forceinline__ u32 pack_bf16(float a, float b) {
    union { bf16 h[2]; u32 w; } u;
    u.h[0] = (bf16)a; u.h[1] = (bf16)b;
    return u.w;
}

// ---------------------------------------------------------------------------
// bf16 MFMA GEMM, 128x128 tile (m97 structure). For N>=1024-ish shapes.
// ---------------------------------------------------------------------------
template <int OP, bool WF32, bool WB16>
__global__ __launch_bounds__(256) void mgemm(
    const bf16* __restrict__ A, const bf16* __restrict__ Bt,
    const float* __restrict__ bias, const float* __restrict__ res,
    float* __restrict__ Cf, bf16* __restrict__ Cb, int M, int N, int K)
{
    __shared__ __align__(16) bf16 As[128 * 32];
    __shared__ __align__(16) bf16 Bs[128 * 32];
    const int tid  = threadIdx.x;
    const int m0   = blockIdx.y * 128;
    const int n0   = blockIdx.x * 128;
    const int wave = tid >> 6, lane = tid & 63;
    const int wm = (wave >> 1) * 64, wn = (wave & 1) * 64;

    f32x4 acc[4][4] = {};

    const int srow = tid >> 2;
    const int scol = (tid & 3) * 8;
    const bf16* Ag = A  + (size_t)(m0 + srow) * K + scol;
    const bf16* Bg = Bt + (size_t)(n0 + srow) * K + scol;
    bf16* Al = &As[tid * 8];
    bf16* Bl = &Bs[tid * 8];
    const size_t half = (size_t)64 * K;

    const int fr = lane & 15;
    const int kq = (lane >> 4) * 8;
    const bf16* pa = &As[(wm + fr) * 32 + kq];
    const bf16* pb = &Bs[(wn + fr) * 32 + kq];

    for (int k0 = 0; k0 < K; k0 += 32) {
        gld16(Ag + k0,        Al);
        gld16(Ag + k0 + half, Al + 64 * 32);
        gld16(Bg + k0,        Bl);
        gld16(Bg + k0 + half, Bl + 64 * 32);
        __syncthreads();

        bf16x8 af[4], bfr[4];
        #pragma unroll
        for (int i = 0; i < 4; ++i) af[i]  = *(const bf16x8*)(pa + i * 16 * 32);
        #pragma unroll
        for (int j = 0; j < 4; ++j) bfr[j] = *(const bf16x8*)(pb + j * 16 * 32);
        #pragma unroll
        for (int i = 0; i < 4; ++i)
            #pragma unroll
            for (int j = 0; j < 4; ++j)
                acc[i][j] = __builtin_amdgcn_mfma_f32_16x16x32_bf16(
                    af[i], bfr[j], acc[i][j], 0, 0, 0);
        __syncthreads();
    }

    const int colb = n0 + wn + (lane & 15);
    const int rowb = m0 + wm + (lane >> 4) * 4;
    #pragma unroll
    for (int i = 0; i < 4; ++i) {
        #pragma unroll
        for (int j = 0; j < 4; ++j) {
            const int c = colb + j * 16;
            const float bj = bias[c];
            #pragma unroll
            for (int r = 0; r < 4; ++r) {
                const int m = rowb + i * 16 + r;
                float v = acc[i][j][r] + bj;
                if (OP == OP_GELU) v = gelu_tanh(v);
                if (OP == OP_RES)  v += res[(size_t)m * N + c];
                if (WF32) Cf[(size_t)m * N + c] = v;
                if (WB16) Cb[(size_t)m * N + c] = (bf16)v;
            }
        }
    }
}

// ---------------------------------------------------------------------------
// bf16 MFMA GEMM, 64x128 tile: doubles grid for occupancy-starved shapes.
// 4 waves as 2(m)x2(n); each wave 32m x 64n (acc 2x4). LDS 12 KB.
// ---------------------------------------------------------------------------
template <int OP, bool WF32, bool WB16>
__global__ __launch_bounds__(256) void mgemm64(
    const bf16* __restrict__ A, const bf16* __restrict__ Bt,
    const float* __restrict__ bias, const float* __restrict__ res,
    float* __restrict__ Cf, bf16* __restrict__ Cb, int M, int N, int K)
{
    __shared__ __align__(16) bf16 As[64 * 32];
    __shared__ __align__(16) bf16 Bs[128 * 32];
    const int tid  = threadIdx.x;
    const int m0   = blockIdx.y * 64;
    const int n0   = blockIdx.x * 128;
    const int wave = tid >> 6, lane = tid & 63;
    const int wm = (wave >> 1) * 32, wn = (wave & 1) * 64;

    f32x4 acc[2][4] = {};

    const int srow = tid >> 2;
    const int scol = (tid & 3) * 8;
    const bf16* Ag = A  + (size_t)(m0 + srow) * K + scol;
    const bf16* Bg = Bt + (size_t)(n0 + srow) * K + scol;
    bf16* Al = &As[tid * 8];
    bf16* Bl = &Bs[tid * 8];
    const size_t half = (size_t)64 * K;

    const int fr = lane & 15;
    const int kq = (lane >> 4) * 8;
    const bf16* pa = &As[(wm + fr) * 32 + kq];
    const bf16* pb = &Bs[(wn + fr) * 32 + kq];

    for (int k0 = 0; k0 < K; k0 += 32) {
        gld16(Ag + k0,        Al);
        gld16(Bg + k0,        Bl);
        gld16(Bg + k0 + half, Bl + 64 * 32);
        __syncthreads();

        bf16x8 af[2], bfr[4];
        #pragma unroll
        for (int i = 0; i < 2; ++i) af[i]  = *(const bf16x8*)(pa + i * 16 * 32);
        #pragma unroll
        for (int j = 0; j < 4; ++j) bfr[j] = *(const bf16x8*)(pb + j * 16 * 32);
        #pragma unroll
        for (int i = 0; i < 2; ++i)
            #pragma unroll
            for (int j = 0; j < 4; ++j)
                acc[i][j] = __builtin_amdgcn_mfma_f32_16x16x32_bf16(
                    af[i], bfr[j], acc[i][j], 0, 0, 0);
        __syncthreads();
    }

    const int colb = n0 + wn + (lane & 15);
    const int rowb = m0 + wm + (lane >> 4) * 4;
    #pragma unroll
    for (int i = 0; i < 2; ++i) {
        #pragma unroll
        for (int j = 0; j < 4; ++j) {
            const int c = colb + j * 16;
            const float bj = bias[c];
            #pragma unroll
            for (int r = 0; r < 4; ++r) {
                const int m = rowb + i * 16 + r;
                float v = acc[i][j][r] + bj;
                if (OP == OP_GELU) v = gelu_tanh(v);
                if (OP == OP_RES)  v += res[(size_t)m * N + c];
                if (WF32) Cf[(size_t)m * N + c] = v;
                if (WB16) Cb[(size_t)m * N + c] = (bf16)v;
            }
        }
    }
}

// ---------------------------------------------------------------------------
// All 9 weight transposes (fp32 KxN -> bf16 NxK) in ONE launch.
// ---------------------------------------------------------------------------
struct TDesc { const float* src; bf16* dst; int K; int N; int tile0; };
struct TDescs { TDesc d[9]; };

__global__ __launch_bounds__(256) void transpose_all(TDescs td)
{
    __shared__ float t[32][33];
    const int blk = blockIdx.x;
    int i = 0;
    #pragma unroll
    for (int j = 1; j < 9; ++j) if (blk >= td.d[j].tile0) i = j;
    const float* src = td.d[i].src;
    bf16* dst = td.d[i].dst;
    const int K = td.d[i].K, N = td.d[i].N;
    const int local = blk - td.d[i].tile0;
    const int ntx = N >> 5;
    const int bx = local % ntx, by = local / ntx;
    const int x = threadIdx.x & 31, y = threadIdx.x >> 5;
    #pragma unroll
    for (int p = 0; p < 32; p += 8)
        t[y + p][x] = src[(size_t)(by * 32 + y + p) * N + bx * 32 + x];
    __syncthreads();
    #pragma unroll
    for (int p = 0; p < 32; p += 8)
        dst[(size_t)(bx * 32 + y + p) * K + by * 32 + x] = (bf16)t[x][y + p];
}

// fp32 -> bf16 elementwise
__global__ __launch_bounds__(256) void cvt_kernel(
    const float* __restrict__ in, bf16* __restrict__ out, int n4)
{
    int i = blockIdx.x * 256 + threadIdx.x;
    if (i >= n4) return;
    float4 v = ((const float4*)in)[i];
    out[4 * i + 0] = (bf16)v.x;
    out[4 * i + 1] = (bf16)v.y;
    out[4 * i + 2] = (bf16)v.z;
    out[4 * i + 3] = (bf16)v.w;
}

// kv = x @ Wm + bm  (K=4), bf16 out.
__global__ __launch_bounds__(256) void kv_kernel(
    const float* __restrict__ x, const float* __restrict__ Wm,
    const float* __restrict__ bm, bf16* __restrict__ kv)
{
    int idx = blockIdx.x * 256 + threadIdx.x;
    int r = idx >> 10, n = idx & 1023;
    float4 xv = *(const float4*)(x + (size_t)r * 4);
    float v = bm[n] + xv.x * Wm[n] + xv.y * Wm[1024 + n]
                    + xv.z * Wm[2048 + n] + xv.w * Wm[3072 + n];
    kv[idx] = (bf16)v;
}

// 3D RoPE: bf16 in (row stride istr, col offset icoff) -> bf16 out (rows x 512).
__global__ __launch_bounds__(256) void rope_b_kernel(
    const bf16* __restrict__ in, bf16* __restrict__ out,
    int tok, int gdiv, int wdiv, int total, float sc, int istr, int icoff)
{
    int idx = blockIdx.x * 256 + threadIdx.x;
    if (idx >= total) return;
    int row = idx >> 7;
    int r2 = idx & 127;
    int h = r2 >> 5;
    int j2 = r2 & 31;
    int j = 2 * j2;
    int n = row % tok;
    int t = n / gdiv;
    int g = n % gdiv;
    int gh = g / wdiv;
    int gw = g % wdiv;
    float pa = (j < 22) ? (float)t : (j < 43) ? (float)gh : (float)gw;
    int j1 = j + 1;
    float pb = (j1 < 22) ? (float)t : (j1 < 43) ? (float)gh : (float)gw;
    float fra = pa * exp2f(-(float)j  * 0.20762050593045954f);
    float frb = pb * exp2f(-(float)j1 * 0.20762050593045954f);
    float ca = cosf(fra), sa = sinf(fra);
    float cb = cosf(frb), sb = sinf(frb);
    size_t ibase = (size_t)row * istr + icoff + (size_t)h * 128 + j;
    size_t obase = (size_t)row * 512 + (size_t)h * 128 + j;
    union { u32 w; bf16 e[2]; } ua, ub;
    ua.w = *(const u32*)(in + ibase);
    ub.w = *(const u32*)(in + ibase + 64);
    float x1a = (float)ua.e[0], x1b = (float)ua.e[1];
    float x2a = (float)ub.e[0], x2b = (float)ub.e[1];
    *(u32*)(out + obase)      = pack_bf16((x1a * ca - x2a * sa) * sc,
                                          (x1b * cb - x2b * sb) * sc);
    *(u32*)(out + obase + 64) = pack_bf16((x2a * ca + x1a * sa) * sc,
                                          (x2b * cb + x1b * sb) * sc);
}

// Coalesced V transpose: kv16[t][512 + h*128 + d] -> Vt[b][h][d][2048]
__global__ __launch_bounds__(256) void vt_tiled(
    const bf16* __restrict__ kv16, bf16* __restrict__ vt)
{
    __shared__ bf16 t[64][72];
    const int tt = blockIdx.x * 64;
    const int d0 = blockIdx.y * 64;
    const int bh = blockIdx.z;
    const int b = bh >> 2, h = bh & 3;
    const int rr = threadIdx.x >> 4;
    const int cc = (threadIdx.x & 15) * 4;
    #pragma unroll
    for (int p = 0; p < 4; ++p) {
        int r = rr + p * 16;
        *(bf16x4*)&t[r][cc] = *(const bf16x4*)
            (kv16 + (size_t)(b * ROWS_K + tt + r) * 1024 + 512 + h * 128 + d0 + cc);
    }
    __syncthreads();
    #pragma unroll
    for (int p = 0; p < 4; ++p) {
        int r = rr + p * 16;   // d-local
        bf16x4 v;
        v[0] = t[cc + 0][r]; v[1] = t[cc + 1][r];
        v[2] = t[cc + 2][r]; v[3] = t[cc + 3][r];
        *(bf16x4*)(vt + (size_t)bh * HD * ROWS_K + (size_t)(d0 + r) * ROWS_K + tt + cc) = v;
    }
}

// LayerNorm in-place on (rows x 512) + bf16 copy.
__global__ __launch_bounds__(256) void ln_kernel(
    float* __restrict__ xb, const float* __restrict__ g,
    const float* __restrict__ be, bf16* __restrict__ out16)
{
    int wave = threadIdx.x >> 6, lane = threadIdx.x & 63;
    size_t row = (size_t)blockIdx.x * 4 + wave;
    float* xp = xb + row * 512;
    float4 a = ((const float4*)xp)[lane];
    float4 b = ((const float4*)xp)[lane + 64];
    float s  = a.x + a.y + a.z + a.w + b.x + b.y + b.z + b.w;
    float sq = a.x*a.x + a.y*a.y + a.z*a.z + a.w*a.w
             + b.x*b.x + b.y*b.y + b.z*b.z + b.w*b.w;
    #pragma unroll
    for (int off = 32; off; off >>= 1) {
        s  += __shfl_xor(s, off);
        sq += __shfl_xor(sq, off);
    }
    float mean = s * (1.0f / 512.0f);
    float var  = sq * (1.0f / 512.0f) - mean * mean;
    float rstd = rsqrtf(var + 1e-5f);
    float4 gv1 = ((const float4*)g)[lane],  gv2 = ((const float4*)g)[lane + 64];
    float4 bv1 = ((const float4*)be)[lane], bv2 = ((const float4*)be)[lane + 64];
    a.x = (a.x - mean) * rstd * gv1.x + bv1.x;
    a.y = (a.y - mean) * rstd * gv1.y + bv1.y;
    a.z = (a.z - mean) * rstd * gv1.z + bv1.z;
    a.w = (a.w - mean) * rstd * gv1.w + bv1.w;
    b.x = (b.x - mean) * rstd * gv2.x + bv2.x;
    b.y = (b.y - mean) * rstd * gv2.y + bv2.y;
    b.z = (b.z - mean) * rstd * gv2.z + bv2.z;
    b.w = (b.w - mean) * rstd * gv2.w + bv2.w;
    ((float4*)xp)[lane]      = a;
    ((float4*)xp)[lane + 64] = b;
    bf16* op = out16 + row * 512;
    *(u32*)(op + lane * 4)       = pack_bf16(a.x, a.y);
    *(u32*)(op + lane * 4 + 2)   = pack_bf16(a.z, a.w);
    *(u32*)(op + 256 + lane * 4)     = pack_bf16(b.x, b.y);
    *(u32*)(op + 256 + lane * 4 + 2) = pack_bf16(b.z, b.w);
}

// ---------------------------------------------------------------------------
// MFMA flash attention (bf16, fp32 accum) — VERBATIM round-0 body (the
// 128-VGPR / 121us schedule). Rounds 1-4 proved any dataflow edit (16q/wave,
// reg-staged dbuf, setprio, defer-branch, split epilogue) knocks regalloc
// into a 56-108 VGPR serialized schedule (3-5x slower). Only two
// codegen-neutral edits vs round 0:
//   1. bid->(b,h,qt) remap: bh = bid&7, qt = bid>>3. HW round-robins blockIdx
//      across the 8 XCDs, so all 49 q-tiles sharing one (b,h) K/V working set
//      (1MB) land on ONE XCD's L2 -> K/V HBM re-fetch (~3x in round 0)
//      becomes local-L2 hits. Worst case (different dispatch policy): neutral.
//   2. LDS stride immediates 136->140 (K,O), 72->76 (V): same live values,
//      conflicts proven 11.4M -> 3.3M across rounds 1-4.
// LDS: 64*140*2 + 128*76*2 = 37376 B.
// ---------------------------------------------------------------------------
#define KS 140
#define VS 76
#define OS 140

__global__ __launch_bounds__(256, 2) void mattn_kernel(
    const bf16* __restrict__ qs, const bf16* __restrict__ ks,
    const bf16* __restrict__ vt, bf16* __restrict__ outb)
{
    __shared__ __align__(16) char smem[37376];
    bf16* Ksh = (bf16*)smem;            // [64][KS]
    bf16* Vsh = (bf16*)(smem + 17920);  // [128][VS]

    const int tid = threadIdx.x;
    const int wave = tid >> 6, lane = tid & 63;
    const int quad = lane >> 4, c = lane & 15;
    const int bid = blockIdx.x;
    const int bh = bid & 7;             // XCD-locality: same (b,h) -> same XCD
    const int qt = bid >> 3;
    const int h  = bh & 3;
    const int b  = bh >> 2;

    const int q0 = qt * 128 + wave * 32;
    const bf16* qg = qs + (size_t)(b * ROWS_Q + q0) * HID + h * HD;
    const bf16* kg = ks + (size_t)(b * ROWS_K) * HID + h * HD;
    const bf16* vg = vt + (size_t)(b * NH + h) * HD * ROWS_K;

    bf16x8 qf[2][4];
    #pragma unroll
    for (int n = 0; n < 2; ++n)
        #pragma unroll
        for (int s = 0; s < 4; ++s)
            qf[n][s] = *(const bf16x8*)(qg + (size_t)(n * 16 + c) * HID + s * 32 + quad * 8);

    f32x4 o[8][2] = {};
    float m_i[2] = {-1e30f, -1e30f}, l_i[2] = {0.0f, 0.0f};

    const int st_t = tid >> 2;
    const int st_d = (tid & 3) * 32;
    const int sv_d = tid >> 1;
    const int sv_t = (tid & 1) * 32;

    for (int kt = 0; kt < 32; ++kt) {
        __syncthreads();
        {
            const bf16* src = kg + (size_t)(kt * 64 + st_t) * HID + st_d;
            bf16* dst = Ksh + st_t * KS + st_d;
            #pragma unroll
            for (int i = 0; i < 4; ++i)
                *(bf16x8*)(dst + i * 8) = *(const bf16x8*)(src + i * 8);
        }
        {
            const bf16* src = vg + (size_t)sv_d * ROWS_K + kt * 64 + sv_t;
            bf16* dst = Vsh + sv_d * VS + sv_t;
            #pragma unroll
            for (int i = 0; i < 4; ++i)
                *(bf16x8*)(dst + i * 8) = *(const bf16x8*)(src + i * 8);
        }
        __syncthreads();

        f32x4 s[4][2] = {};
        #pragma unroll
        for (int ksi = 0; ksi < 4; ++ksi) {
            bf16x8 kf[4];
            #pragma unroll
            for (int mi = 0; mi < 4; ++mi)
                kf[mi] = *(const bf16x8*)(Ksh + (mi * 16 + c) * KS + ksi * 32 + quad * 8);
            #pragma unroll
            for (int mi = 0; mi < 4; ++mi)
                #pragma unroll
                for (int n = 0; n < 2; ++n)
                    s[mi][n] = __builtin_amdgcn_mfma_f32_16x16x32_bf16(
                        kf[mi], qf[n][ksi], s[mi][n], 0, 0, 0);
        }

        float alpha[2];
        #pragma unroll
        for (int n = 0; n < 2; ++n) {
            float mx = -1e30f;
            #pragma unroll
            for (int mi = 0; mi < 4; ++mi)
                #pragma unroll
                for (int r = 0; r < 4; ++r) mx = fmaxf(mx, s[mi][n][r]);
            mx = fmaxf(mx, __shfl_xor(mx, 16));
            mx = fmaxf(mx, __shfl_xor(mx, 32));
            float mn = fmaxf(m_i[n], mx);
            alpha[n] = __expf(m_i[n] - mn);
            m_i[n] = mn;
            float sm = 0.0f;
            #pragma unroll
            for (int mi = 0; mi < 4; ++mi)
                #pragma unroll
                for (int r = 0; r < 4; ++r) {
                    float p = __expf(s[mi][n][r] - mn);
                    s[mi][n][r] = p;
                    sm += p;
                }
            sm += __shfl_xor(sm, 16);
            sm += __shfl_xor(sm, 32);
            l_i[n] = l_i[n] * alpha[n] + sm;
            #pragma unroll
            for (int md = 0; md < 8; ++md) {
                o[md][n][0] *= alpha[n]; o[md][n][1] *= alpha[n];
                o[md][n][2] *= alpha[n]; o[md][n][3] *= alpha[n];
            }
        }

        u32 pk[4][2][2];
        #pragma unroll
        for (int mi = 0; mi < 4; ++mi)
            #pragma unroll
            for (int n = 0; n < 2; ++n) {
                pk[mi][n][0] = pack_bf16(s[mi][n][0], s[mi][n][1]);
                pk[mi][n][1] = pack_bf16(s[mi][n][2], s[mi][n][3]);
            }
        bf16x8 pf[2][2];
        #pragma unroll
        for (int kst = 0; kst < 2; ++kst)
            #pragma unroll
            for (int n = 0; n < 2; ++n) {
                union { bf16x8 v8; u32 d[4]; } u;
                #pragma unroll
                for (int dw = 0; dw < 4; ++dw) {
                    int srcl = ((quad & 1) * 2 + (dw >> 1)) * 16 + c;
                    u32 lo = (u32)__shfl((int)pk[2 * kst][n][dw & 1], srcl);
                    u32 hi = (u32)__shfl((int)pk[2 * kst + 1][n][dw & 1], srcl);
                    u.d[dw] = (quad >= 2) ? hi : lo;
                }
                pf[kst][n] = u.v8;
            }

        #pragma unroll
        for (int kst = 0; kst < 2; ++kst)
            #pragma unroll
            for (int md = 0; md < 8; ++md) {
                bf16x8 vf = *(const bf16x8*)(Vsh + (md * 16 + c) * VS + kst * 32 + quad * 8);
                #pragma unroll
                for (int n = 0; n < 2; ++n)
                    o[md][n] = __builtin_amdgcn_mfma_f32_16x16x32_bf16(
                        vf, pf[kst][n], o[md][n], 0, 0, 0);
            }
    }

    __syncthreads();
    bf16* Osh = (bf16*)smem + wave * (32 * OS);
    float inv[2] = {1.0f / l_i[0], 1.0f / l_i[1]};
    #pragma unroll
    for (int md = 0; md < 8; ++md)
        #pragma unroll
        for (int n = 0; n < 2; ++n)
            #pragma unroll
            for (int hh = 0; hh < 2; ++hh) {
                u32 w = pack_bf16(o[md][n][2 * hh] * inv[n], o[md][n][2 * hh + 1] * inv[n]);
                int d = md * 16 + quad * 4 + 2 * hh;
                int qq = n * 16 + c;
                *(u32*)(Osh + qq * OS + d) = w;
            }
    __syncthreads();
    bf16* og = outb + (size_t)(b * ROWS_Q + q0) * HID + h * HD;
    #pragma unroll
    for (int i = 0; i < 8; ++i) {
        int idx = i * 64 + lane;
        int qq = idx >> 4;
        int ch = idx & 15;
        bf16x8 vv = *(const bf16x8*)(Osh + qq * OS + ch * 8);
        *(bf16x8*)(og + (size_t)qq * HID + ch * 8) = vv;
    }
}

extern "C" void kernel_launch(void* const* d_in, const int* in_sizes, int n_in,
                              void* d_out, int out_size, void* d_ws, size_t ws_size,
                              hipStream_t stream)
{
    const float* x     = (const float*)d_in[0];
    const float* slow  = (const float*)d_in[1];
    const float* Wq_in = (const float*)d_in[3];
    const float* bq_in = (const float*)d_in[4];
    const float* Wm    = (const float*)d_in[5];
    const float* bm    = (const float*)d_in[6];
    const float* Wq    = (const float*)d_in[7];
    const float* bq    = (const float*)d_in[8];
    const float* Wk    = (const float*)d_in[9];
    const float* bk    = (const float*)d_in[10];
    const float* Wv    = (const float*)d_in[11];
    const float* bv    = (const float*)d_in[12];
    const float* Wo    = (const float*)d_in[13];
    const float* bo    = (const float*)d_in[14];
    const float* g1    = (const float*)d_in[15];
    const float* be1   = (const float*)d_in[16];
    const float* W1    = (const float*)d_in[17];
    const float* b1    = (const float*)d_in[18];
    const float* W2    = (const float*)d_in[19];
    const float* b2    = (const float*)d_in[20];
    const float* g2    = (const float*)d_in[21];
    const float* be2   = (const float*)d_in[22];
    const float* M1    = (const float*)d_in[23];
    const float* bm1   = (const float*)d_in[24];
    const float* M2    = (const float*)d_in[25];
    const float* bm2   = (const float*)d_in[26];
    float* out = (float*)d_out;

    // ---- workspace layout ----
    float* q_in_f = (float*)d_ws;                         // MQ*512 f32
    float* ob     = q_in_f + (size_t)MQ * HID;            // MQ*512 f32
    float* bkv    = ob + (size_t)MQ * HID;                // 1024 f32
    bf16* shared_b = (bf16*)(bkv + 1024);                 // MQ*1024 (slow_b/attn_b/ff1_b/m1_b)
    bf16* q_in_b = shared_b + (size_t)MQ * FF;            // MQ*512
    bf16* kv_b   = q_in_b + (size_t)MQ * HID;             // MK*1024
    bf16* h_b    = kv_b + (size_t)MK * EMB;               // MQ*512
    bf16* q16    = h_b + (size_t)MQ * HID;                // MQ*512
    bf16* kv16   = q16 + (size_t)MQ * HID;                // MK*1024 (k|v fused)
    bf16* qbt    = kv16 + (size_t)MK * EMB;               // MQ*512
    bf16* kbt    = qbt + (size_t)MQ * HID;                // MK*512
    bf16* Vt     = kbt + (size_t)MK * HID;                // 8*128*2048
    bf16* Wq_in_t = Vt + (size_t)8 * HD * ROWS_K;         // 512*896
    bf16* Wq_t  = Wq_in_t + 512 * 896;                    // 512*512
    bf16* kvw_t = Wq_t + 512 * 512;                       // 1024*1024 (Wk_t | Wv_t)
    bf16* Wo_t  = kvw_t + 1024 * 1024;                    // 512*512
    bf16* W1_t  = Wo_t + 512 * 512;                       // 1024*512
    bf16* W2_t  = W1_t + 1024 * 512;                      // 512*1024
    bf16* M1_t  = W2_t + 512 * 1024;                      // 1024*512
    bf16* M2_t  = M1_t + 1024 * 512;                      // 896*1024
    bf16* slow_b = shared_b;
    bf16* attn_b = shared_b;
    bf16* ff1_b  = shared_b;
    bf16* m1_b   = shared_b;

    dim3 blk(256);

    // ---- all weight transposes in one launch ----
    TDescs td;
    int t0 = 0;
    auto set = [&](int i, const float* s, bf16* d, int K, int N) {
        td.d[i] = {s, d, K, N, t0};
        t0 += (N / 32) * (K / 32);
    };
    set(0, Wq_in, Wq_in_t, 896, 512);
    set(1, Wq,    Wq_t,    512, 512);
    set(2, Wk,    kvw_t,              1024, 512);
    set(3, Wv,    kvw_t + 512 * 1024, 1024, 512);
    set(4, Wo,    Wo_t,    512, 512);
    set(5, W1,    W1_t,    512, 1024);
    set(6, W2,    W2_t,    1024, 512);
    set(7, M1,    M1_t,    512, 1024);
    set(8, M2,    M2_t,    1024, 896);
    transpose_all<<<t0, blk, 0, stream>>>(td);

    // bias concat for fused KV GEMM
    hipMemcpyAsync(bkv,       bk, 512 * sizeof(float), hipMemcpyDeviceToDevice, stream);
    hipMemcpyAsync(bkv + 512, bv, 512 * sizeof(float), hipMemcpyDeviceToDevice, stream);

    cvt_kernel<<<(MQ * DQ / 4 + 255) / 256, blk, 0, stream>>>(slow, slow_b, MQ * DQ / 4);
    kv_kernel<<<(MK * EMB) / 256, blk, 0, stream>>>(x, Wm, bm, kv_b);

    // q_in = slow @ Wq_in + bq_in -> fp32 (residual) + bf16   grid 4x196
    mgemm64<OP_BIAS, true, true><<<dim3(4, 196), blk, 0, stream>>>(
        slow_b, Wq_in_t, bq_in, nullptr, q_in_f, q_in_b, MQ, HID, DQ);
    // q projection -> bf16   grid 4x196
    mgemm64<OP_BIAS, false, true><<<dim3(4, 196), blk, 0, stream>>>(
        q_in_b, Wq_t, bq, nullptr, nullptr, q16, MQ, HID, HID);
    // fused k|v projection -> kv16 (MK x 1024)   grid 8x64
    mgemm64<OP_BIAS, false, true><<<dim3(8, 64), blk, 0, stream>>>(
        kv_b, kvw_t, bkv, nullptr, nullptr, kv16, MK, 1024, EMB);
    // RoPE (q pre-scaled by 1/sqrt(128)); k read from fused kv16
    rope_b_kernel<<<(MQ * 128 + 255) / 256, blk, 0, stream>>>(
        q16, qbt, ROWS_Q, 196, 14, MQ * 128, 0.08838834764831843f, 512, 0);
    rope_b_kernel<<<(MK * 128 + 255) / 256, blk, 0, stream>>>(
        kv16, kbt, ROWS_K, 64, 8, MK * 128, 1.0f, 1024, 0);
    // V transpose (coalesced)
    vt_tiled<<<dim3(32, 2, 8), blk, 0, stream>>>(kv16, Vt);
    // MFMA flash attention -> attn_b (bf16), grid 392
    mattn_kernel<<<dim3(392), blk, 0, stream>>>(qbt, kbt, Vt, attn_b);
    // pre_ln = attn @ Wo + bo + q_in   grid 4x196
    mgemm64<OP_RES, true, false><<<dim3(4, 196), blk, 0, stream>>>(
        attn_b, Wo_t, bo, q_in_f, ob, nullptr, MQ, HID, HID);
    ln_kernel<<<MQ / 4, blk, 0, stream>>>(ob, g1, be1, h_b);
    // ff1 = gelu(h @ W1 + b1)   grid 8x98 (128-tile)
    mgemm<OP_GELU, false, true><<<dim3(8, 98), blk, 0, stream>>>(
        h_b, W1_t, b1, nullptr, nullptr, ff1_b, MQ, FF, HID);
    // pre2 = ff1 @ W2 + b2 + h   grid 4x196
    mgemm64<OP_RES, true, false><<<dim3(4, 196), blk, 0, stream>>>(
        ff1_b, W2_t, b2, ob, q_in_f, nullptr, MQ, HID, FF);
    ln_kernel<<<MQ / 4, blk, 0, stream>>>(q_in_f, g2, be2, h_b);
    // m1 = gelu(h2 @ M1 + bm1)   grid 8x98
    mgemm<OP_GELU, false, true><<<dim3(8, 98), blk, 0, stream>>>(
        h_b, M1_t, bm1, nullptr, nullptr, m1_b, MQ, 2 * HID, HID);
    // out = m1 @ M2 + bm2   grid 7x98
    mgemm<OP_BIAS, true, false><<<dim3(7, 98), blk, 0, stream>>>(
        m1_b, M2_t, bm2, nullptr, out, nullptr, MQ, OUTD, 2 * HID);
}

// Round 6
// 585.821 us; speedup vs baseline: 1.3738x; 1.3738x over previous
//
#include <hip/hip_runtime.h>
#include <cstdint>
#include <cstddef>

// ---------------- dims ----------------
#define BATCH 2
#define MQ 12544          // B * TQ * NQ
#define ROWS_Q 6272
#define MK 4096           // B * T*H*W
#define ROWS_K 2048
#define HID 512
#define NH 4
#define HD 128
#define EMB 1024
#define DQ 896
#define FF 1024
#define OUTD 896

typedef __bf16 bf16;
typedef unsigned int u32;
typedef bf16 bf16x8 __attribute__((ext_vector_type(8)));
typedef bf16 bf16x4 __attribute__((ext_vector_type(4)));
typedef float f32x4 __attribute__((ext_vector_type(4)));

enum { OP_BIAS = 0, OP_GELU = 1, OP_RES = 2 };

__device__ __forceinline__ float gelu_tanh(float x) {
    float x3 = x * x * x;
    return 0.5f * x * (1.0f + tanhf(0.7978845608028654f * (x + 0.044715f * x3)));
}

__device__ __forceinline__ void gld16(const bf16* g, bf16* l) {
    __builtin_amdgcn_global_load_lds(
        (const __attribute__((address_space(1))) unsigned int*)g,
        (__attribute__((address_space(3))) unsigned int*)l, 16, 0, 0);
}

__device__ __forceinline__ u32 pack_bf16(float a, float b) {
    union { bf16 h[2]; u32 w; } u;
    u.h[0] = (bf16)a; u.h[1] = (bf16)b;
    return u.w;
}

// ---------------------------------------------------------------------------
// bf16 MFMA GEMM, 128x128 tile (m97 structure). For N>=1024-ish shapes.
// ---------------------------------------------------------------------------
template <int OP, bool WF32, bool WB16>
__global__ __launch_bounds__(256) void mgemm(
    const bf16* __restrict__ A, const bf16* __restrict__ Bt,
    const float* __restrict__ bias, const float* __restrict__ res,
    float* __restrict__ Cf, bf16* __restrict__ Cb, int M, int N, int K)
{
    __shared__ __align__(16) bf16 As[128 * 32];
    __shared__ __align__(16) bf16 Bs[128 * 32];
    const int tid  = threadIdx.x;
    const int m0   = blockIdx.y * 128;
    const int n0   = blockIdx.x * 128;
    const int wave = tid >> 6, lane = tid & 63;
    const int wm = (wave >> 1) * 64, wn = (wave & 1) * 64;

    f32x4 acc[4][4] = {};

    const int srow = tid >> 2;
    const int scol = (tid & 3) * 8;
    const bf16* Ag = A  + (size_t)(m0 + srow) * K + scol;
    const bf16* Bg = Bt + (size_t)(n0 + srow) * K + scol;
    bf16* Al = &As[tid * 8];
    bf16* Bl = &Bs[tid * 8];
    const size_t half = (size_t)64 * K;

    const int fr = lane & 15;
    const int kq = (lane >> 4) * 8;
    const bf16* pa = &As[(wm + fr) * 32 + kq];
    const bf16* pb = &Bs[(wn + fr) * 32 + kq];

    for (int k0 = 0; k0 < K; k0 += 32) {
        gld16(Ag + k0,        Al);
        gld16(Ag + k0 + half, Al + 64 * 32);
        gld16(Bg + k0,        Bl);
        gld16(Bg + k0 + half, Bl + 64 * 32);
        __syncthreads();

        bf16x8 af[4], bfr[4];
        #pragma unroll
        for (int i = 0; i < 4; ++i) af[i]  = *(const bf16x8*)(pa + i * 16 * 32);
        #pragma unroll
        for (int j = 0; j < 4; ++j) bfr[j] = *(const bf16x8*)(pb + j * 16 * 32);
        #pragma unroll
        for (int i = 0; i < 4; ++i)
            #pragma unroll
            for (int j = 0; j < 4; ++j)
                acc[i][j] = __builtin_amdgcn_mfma_f32_16x16x32_bf16(
                    af[i], bfr[j], acc[i][j], 0, 0, 0);
        __syncthreads();
    }

    const int colb = n0 + wn + (lane & 15);
    const int rowb = m0 + wm + (lane >> 4) * 4;
    #pragma unroll
    for (int i = 0; i < 4; ++i) {
        #pragma unroll
        for (int j = 0; j < 4; ++j) {
            const int c = colb + j * 16;
            const float bj = bias[c];
            #pragma unroll
            for (int r = 0; r < 4; ++r) {
                const int m = rowb + i * 16 + r;
                float v = acc[i][j][r] + bj;
                if (OP == OP_GELU) v = gelu_tanh(v);
                if (OP == OP_RES)  v += res[(size_t)m * N + c];
                if (WF32) Cf[(size_t)m * N + c] = v;
                if (WB16) Cb[(size_t)m * N + c] = (bf16)v;
            }
        }
    }
}

// ---------------------------------------------------------------------------
// bf16 MFMA GEMM, 64x128 tile: doubles grid for occupancy-starved shapes.
// 4 waves as 2(m)x2(n); each wave 32m x 64n (acc 2x4). LDS 12 KB.
// ---------------------------------------------------------------------------
template <int OP, bool WF32, bool WB16>
__global__ __launch_bounds__(256) void mgemm64(
    const bf16* __restrict__ A, const bf16* __restrict__ Bt,
    const float* __restrict__ bias, const float* __restrict__ res,
    float* __restrict__ Cf, bf16* __restrict__ Cb, int M, int N, int K)
{
    __shared__ __align__(16) bf16 As[64 * 32];
    __shared__ __align__(16) bf16 Bs[128 * 32];
    const int tid  = threadIdx.x;
    const int m0   = blockIdx.y * 64;
    const int n0   = blockIdx.x * 128;
    const int wave = tid >> 6, lane = tid & 63;
    const int wm = (wave >> 1) * 32, wn = (wave & 1) * 64;

    f32x4 acc[2][4] = {};

    const int srow = tid >> 2;
    const int scol = (tid & 3) * 8;
    const bf16* Ag = A  + (size_t)(m0 + srow) * K + scol;
    const bf16* Bg = Bt + (size_t)(n0 + srow) * K + scol;
    bf16* Al = &As[tid * 8];
    bf16* Bl = &Bs[tid * 8];
    const size_t half = (size_t)64 * K;

    const int fr = lane & 15;
    const int kq = (lane >> 4) * 8;
    const bf16* pa = &As[(wm + fr) * 32 + kq];
    const bf16* pb = &Bs[(wn + fr) * 32 + kq];

    for (int k0 = 0; k0 < K; k0 += 32) {
        gld16(Ag + k0,        Al);
        gld16(Bg + k0,        Bl);
        gld16(Bg + k0 + half, Bl + 64 * 32);
        __syncthreads();

        bf16x8 af[2], bfr[4];
        #pragma unroll
        for (int i = 0; i < 2; ++i) af[i]  = *(const bf16x8*)(pa + i * 16 * 32);
        #pragma unroll
        for (int j = 0; j < 4; ++j) bfr[j] = *(const bf16x8*)(pb + j * 16 * 32);
        #pragma unroll
        for (int i = 0; i < 2; ++i)
            #pragma unroll
            for (int j = 0; j < 4; ++j)
                acc[i][j] = __builtin_amdgcn_mfma_f32_16x16x32_bf16(
                    af[i], bfr[j], acc[i][j], 0, 0, 0);
        __syncthreads();
    }

    const int colb = n0 + wn + (lane & 15);
    const int rowb = m0 + wm + (lane >> 4) * 4;
    #pragma unroll
    for (int i = 0; i < 2; ++i) {
        #pragma unroll
        for (int j = 0; j < 4; ++j) {
            const int c = colb + j * 16;
            const float bj = bias[c];
            #pragma unroll
            for (int r = 0; r < 4; ++r) {
                const int m = rowb + i * 16 + r;
                float v = acc[i][j][r] + bj;
                if (OP == OP_GELU) v = gelu_tanh(v);
                if (OP == OP_RES)  v += res[(size_t)m * N + c];
                if (WF32) Cf[(size_t)m * N + c] = v;
                if (WB16) Cb[(size_t)m * N + c] = (bf16)v;
            }
        }
    }
}

// ---------------------------------------------------------------------------
// All 9 weight transposes (fp32 KxN -> bf16 NxK) in ONE launch.
// ---------------------------------------------------------------------------
struct TDesc { const float* src; bf16* dst; int K; int N; int tile0; };
struct TDescs { TDesc d[9]; };

__global__ __launch_bounds__(256) void transpose_all(TDescs td)
{
    __shared__ float t[32][33];
    const int blk = blockIdx.x;
    int i = 0;
    #pragma unroll
    for (int j = 1; j < 9; ++j) if (blk >= td.d[j].tile0) i = j;
    const float* src = td.d[i].src;
    bf16* dst = td.d[i].dst;
    const int K = td.d[i].K, N = td.d[i].N;
    const int local = blk - td.d[i].tile0;
    const int ntx = N >> 5;
    const int bx = local % ntx, by = local / ntx;
    const int x = threadIdx.x & 31, y = threadIdx.x >> 5;
    #pragma unroll
    for (int p = 0; p < 32; p += 8)
        t[y + p][x] = src[(size_t)(by * 32 + y + p) * N + bx * 32 + x];
    __syncthreads();
    #pragma unroll
    for (int p = 0; p < 32; p += 8)
        dst[(size_t)(bx * 32 + y + p) * K + by * 32 + x] = (bf16)t[x][y + p];
}

// fp32 -> bf16 elementwise
__global__ __launch_bounds__(256) void cvt_kernel(
    const float* __restrict__ in, bf16* __restrict__ out, int n4)
{
    int i = blockIdx.x * 256 + threadIdx.x;
    if (i >= n4) return;
    float4 v = ((const float4*)in)[i];
    out[4 * i + 0] = (bf16)v.x;
    out[4 * i + 1] = (bf16)v.y;
    out[4 * i + 2] = (bf16)v.z;
    out[4 * i + 3] = (bf16)v.w;
}

// kv = x @ Wm + bm  (K=4), bf16 out.
__global__ __launch_bounds__(256) void kv_kernel(
    const float* __restrict__ x, const float* __restrict__ Wm,
    const float* __restrict__ bm, bf16* __restrict__ kv)
{
    int idx = blockIdx.x * 256 + threadIdx.x;
    int r = idx >> 10, n = idx & 1023;
    float4 xv = *(const float4*)(x + (size_t)r * 4);
    float v = bm[n] + xv.x * Wm[n] + xv.y * Wm[1024 + n]
                    + xv.z * Wm[2048 + n] + xv.w * Wm[3072 + n];
    kv[idx] = (bf16)v;
}

// 3D RoPE: bf16 in (row stride istr, col offset icoff) -> bf16 out (rows x 512).
__global__ __launch_bounds__(256) void rope_b_kernel(
    const bf16* __restrict__ in, bf16* __restrict__ out,
    int tok, int gdiv, int wdiv, int total, float sc, int istr, int icoff)
{
    int idx = blockIdx.x * 256 + threadIdx.x;
    if (idx >= total) return;
    int row = idx >> 7;
    int r2 = idx & 127;
    int h = r2 >> 5;
    int j2 = r2 & 31;
    int j = 2 * j2;
    int n = row % tok;
    int t = n / gdiv;
    int g = n % gdiv;
    int gh = g / wdiv;
    int gw = g % wdiv;
    float pa = (j < 22) ? (float)t : (j < 43) ? (float)gh : (float)gw;
    int j1 = j + 1;
    float pb = (j1 < 22) ? (float)t : (j1 < 43) ? (float)gh : (float)gw;
    float fra = pa * exp2f(-(float)j  * 0.20762050593045954f);
    float frb = pb * exp2f(-(float)j1 * 0.20762050593045954f);
    float ca = cosf(fra), sa = sinf(fra);
    float cb = cosf(frb), sb = sinf(frb);
    size_t ibase = (size_t)row * istr + icoff + (size_t)h * 128 + j;
    size_t obase = (size_t)row * 512 + (size_t)h * 128 + j;
    union { u32 w; bf16 e[2]; } ua, ub;
    ua.w = *(const u32*)(in + ibase);
    ub.w = *(const u32*)(in + ibase + 64);
    float x1a = (float)ua.e[0], x1b = (float)ua.e[1];
    float x2a = (float)ub.e[0], x2b = (float)ub.e[1];
    *(u32*)(out + obase)      = pack_bf16((x1a * ca - x2a * sa) * sc,
                                          (x1b * cb - x2b * sb) * sc);
    *(u32*)(out + obase + 64) = pack_bf16((x2a * ca + x1a * sa) * sc,
                                          (x2b * cb + x1b * sb) * sc);
}

// Coalesced V transpose: kv16[t][512 + h*128 + d] -> Vt[b][h][d][2048]
__global__ __launch_bounds__(256) void vt_tiled(
    const bf16* __restrict__ kv16, bf16* __restrict__ vt)
{
    __shared__ bf16 t[64][72];
    const int tt = blockIdx.x * 64;
    const int d0 = blockIdx.y * 64;
    const int bh = blockIdx.z;
    const int b = bh >> 2, h = bh & 3;
    const int rr = threadIdx.x >> 4;
    const int cc = (threadIdx.x & 15) * 4;
    #pragma unroll
    for (int p = 0; p < 4; ++p) {
        int r = rr + p * 16;
        *(bf16x4*)&t[r][cc] = *(const bf16x4*)
            (kv16 + (size_t)(b * ROWS_K + tt + r) * 1024 + 512 + h * 128 + d0 + cc);
    }
    __syncthreads();
    #pragma unroll
    for (int p = 0; p < 4; ++p) {
        int r = rr + p * 16;   // d-local
        bf16x4 v;
        v[0] = t[cc + 0][r]; v[1] = t[cc + 1][r];
        v[2] = t[cc + 2][r]; v[3] = t[cc + 3][r];
        *(bf16x4*)(vt + (size_t)bh * HD * ROWS_K + (size_t)(d0 + r) * ROWS_K + tt + cc) = v;
    }
}

// LayerNorm in-place on (rows x 512) + bf16 copy.
__global__ __launch_bounds__(256) void ln_kernel(
    float* __restrict__ xb, const float* __restrict__ g,
    const float* __restrict__ be, bf16* __restrict__ out16)
{
    int wave = threadIdx.x >> 6, lane = threadIdx.x & 63;
    size_t row = (size_t)blockIdx.x * 4 + wave;
    float* xp = xb + row * 512;
    float4 a = ((const float4*)xp)[lane];
    float4 b = ((const float4*)xp)[lane + 64];
    float s  = a.x + a.y + a.z + a.w + b.x + b.y + b.z + b.w;
    float sq = a.x*a.x + a.y*a.y + a.z*a.z + a.w*a.w
             + b.x*b.x + b.y*b.y + b.z*b.z + b.w*b.w;
    #pragma unroll
    for (int off = 32; off; off >>= 1) {
        s  += __shfl_xor(s, off);
        sq += __shfl_xor(sq, off);
    }
    float mean = s * (1.0f / 512.0f);
    float var  = sq * (1.0f / 512.0f) - mean * mean;
    float rstd = rsqrtf(var + 1e-5f);
    float4 gv1 = ((const float4*)g)[lane],  gv2 = ((const float4*)g)[lane + 64];
    float4 bv1 = ((const float4*)be)[lane], bv2 = ((const float4*)be)[lane + 64];
    a.x = (a.x - mean) * rstd * gv1.x + bv1.x;
    a.y = (a.y - mean) * rstd * gv1.y + bv1.y;
    a.z = (a.z - mean) * rstd * gv1.z + bv1.z;
    a.w = (a.w - mean) * rstd * gv1.w + bv1.w;
    b.x = (b.x - mean) * rstd * gv2.x + bv2.x;
    b.y = (b.y - mean) * rstd * gv2.y + bv2.y;
    b.z = (b.z - mean) * rstd * gv2.z + bv2.z;
    b.w = (b.w - mean) * rstd * gv2.w + bv2.w;
    ((float4*)xp)[lane]      = a;
    ((float4*)xp)[lane + 64] = b;
    bf16* op = out16 + row * 512;
    *(u32*)(op + lane * 4)       = pack_bf16(a.x, a.y);
    *(u32*)(op + lane * 4 + 2)   = pack_bf16(a.z, a.w);
    *(u32*)(op + 256 + lane * 4)     = pack_bf16(b.x, b.y);
    *(u32*)(op + 256 + lane * 4 + 2) = pack_bf16(b.z, b.w);
}

// ---------------------------------------------------------------------------
// MFMA flash attention, KV-split-2. Inner loop = VERBATIM round-0 body with
// round-0 LDS strides 136/72/136 (16B-aligned rows). Round-5 isolated the
// rounds-1..5 regression: "padded" strides 140/76 made the LDS row pitch
// 8 mod 16 bytes -> misaligned ds_*_b128 slow path (3x on all LDS traffic,
// uniformly ~330-345us regardless of VGPR count). Round-5 also proved
// prologue/epilogue/mapping edits keep the good 128-VGPR loop schedule.
// So: only loop BOUNDS change (part*16 .. part*16+16) + partial epilogue.
//   grid 784 = 2 parts x (2b x 4h x 49 qt): ~3 blocks/CU (12 waves/CU) vs
//   round-0's 1.5 (6 waves/CU, Occupancy 14% -> the round-0 bottleneck).
// Partials written NORMALIZED (o/l, bf16, round-0 epilogue unchanged) plus
// per-row m,l; comb_kernel merges convexly (validated round 4, same absmax).
// NO setprio, NO defer-rescale, NO XCD swizzle, NO stride padding.
// ---------------------------------------------------------------------------
__global__ __launch_bounds__(256, 2) void mattn_kernel(
    const bf16* __restrict__ qs, const bf16* __restrict__ ks,
    const bf16* __restrict__ vt, bf16* __restrict__ op0,
    bf16* __restrict__ op1, float* __restrict__ mbuf,
    float* __restrict__ lbuf)
{
    __shared__ __align__(16) char smem[35840];
    bf16* Ksh = (bf16*)smem;            // [64][136]
    bf16* Vsh = (bf16*)(smem + 17408);  // [128][72]

    const int tid = threadIdx.x;
    const int wave = tid >> 6, lane = tid & 63;
    const int quad = lane >> 4, c = lane & 15;
    const int bid = blockIdx.x;
    const int qt = bid % 49;
    const int h  = (bid / 49) & 3;
    const int rest = bid / 196;         // 0..3
    const int b    = rest & 1;
    const int part = rest >> 1;

    const int q0 = qt * 128 + wave * 32;
    const bf16* qg = qs + (size_t)(b * ROWS_Q + q0) * HID + h * HD;
    const bf16* kg = ks + (size_t)(b * ROWS_K) * HID + h * HD;
    const bf16* vg = vt + (size_t)(b * NH + h) * HD * ROWS_K;

    bf16x8 qf[2][4];
    #pragma unroll
    for (int n = 0; n < 2; ++n)
        #pragma unroll
        for (int s = 0; s < 4; ++s)
            qf[n][s] = *(const bf16x8*)(qg + (size_t)(n * 16 + c) * HID + s * 32 + quad * 8);

    f32x4 o[8][2] = {};
    float m_i[2] = {-1e30f, -1e30f}, l_i[2] = {0.0f, 0.0f};

    const int st_t = tid >> 2;
    const int st_d = (tid & 3) * 32;
    const int sv_d = tid >> 1;
    const int sv_t = (tid & 1) * 32;

    const int kt0 = part * 16;
    for (int kt = kt0; kt < kt0 + 16; ++kt) {
        __syncthreads();
        {
            const bf16* src = kg + (size_t)(kt * 64 + st_t) * HID + st_d;
            bf16* dst = Ksh + st_t * 136 + st_d;
            #pragma unroll
            for (int i = 0; i < 4; ++i)
                *(bf16x8*)(dst + i * 8) = *(const bf16x8*)(src + i * 8);
        }
        {
            const bf16* src = vg + (size_t)sv_d * ROWS_K + kt * 64 + sv_t;
            bf16* dst = Vsh + sv_d * 72 + sv_t;
            #pragma unroll
            for (int i = 0; i < 4; ++i)
                *(bf16x8*)(dst + i * 8) = *(const bf16x8*)(src + i * 8);
        }
        __syncthreads();

        f32x4 s[4][2] = {};
        #pragma unroll
        for (int ksi = 0; ksi < 4; ++ksi) {
            bf16x8 kf[4];
            #pragma unroll
            for (int mi = 0; mi < 4; ++mi)
                kf[mi] = *(const bf16x8*)(Ksh + (mi * 16 + c) * 136 + ksi * 32 + quad * 8);
            #pragma unroll
            for (int mi = 0; mi < 4; ++mi)
                #pragma unroll
                for (int n = 0; n < 2; ++n)
                    s[mi][n] = __builtin_amdgcn_mfma_f32_16x16x32_bf16(
                        kf[mi], qf[n][ksi], s[mi][n], 0, 0, 0);
        }

        float alpha[2];
        #pragma unroll
        for (int n = 0; n < 2; ++n) {
            float mx = -1e30f;
            #pragma unroll
            for (int mi = 0; mi < 4; ++mi)
                #pragma unroll
                for (int r = 0; r < 4; ++r) mx = fmaxf(mx, s[mi][n][r]);
            mx = fmaxf(mx, __shfl_xor(mx, 16));
            mx = fmaxf(mx, __shfl_xor(mx, 32));
            float mn = fmaxf(m_i[n], mx);
            alpha[n] = __expf(m_i[n] - mn);
            m_i[n] = mn;
            float sm = 0.0f;
            #pragma unroll
            for (int mi = 0; mi < 4; ++mi)
                #pragma unroll
                for (int r = 0; r < 4; ++r) {
                    float p = __expf(s[mi][n][r] - mn);
                    s[mi][n][r] = p;
                    sm += p;
                }
            sm += __shfl_xor(sm, 16);
            sm += __shfl_xor(sm, 32);
            l_i[n] = l_i[n] * alpha[n] + sm;
            #pragma unroll
            for (int md = 0; md < 8; ++md) {
                o[md][n][0] *= alpha[n]; o[md][n][1] *= alpha[n];
                o[md][n][2] *= alpha[n]; o[md][n][3] *= alpha[n];
            }
        }

        u32 pk[4][2][2];
        #pragma unroll
        for (int mi = 0; mi < 4; ++mi)
            #pragma unroll
            for (int n = 0; n < 2; ++n) {
                pk[mi][n][0] = pack_bf16(s[mi][n][0], s[mi][n][1]);
                pk[mi][n][1] = pack_bf16(s[mi][n][2], s[mi][n][3]);
            }
        bf16x8 pf[2][2];
        #pragma unroll
        for (int kst = 0; kst < 2; ++kst)
            #pragma unroll
            for (int n = 0; n < 2; ++n) {
                union { bf16x8 v8; u32 d[4]; } u;
                #pragma unroll
                for (int dw = 0; dw < 4; ++dw) {
                    int srcl = ((quad & 1) * 2 + (dw >> 1)) * 16 + c;
                    u32 lo = (u32)__shfl((int)pk[2 * kst][n][dw & 1], srcl);
                    u32 hi = (u32)__shfl((int)pk[2 * kst + 1][n][dw & 1], srcl);
                    u.d[dw] = (quad >= 2) ? hi : lo;
                }
                pf[kst][n] = u.v8;
            }

        #pragma unroll
        for (int kst = 0; kst < 2; ++kst)
            #pragma unroll
            for (int md = 0; md < 8; ++md) {
                bf16x8 vf = *(const bf16x8*)(Vsh + (md * 16 + c) * 72 + kst * 32 + quad * 8);
                #pragma unroll
                for (int n = 0; n < 2; ++n)
                    o[md][n] = __builtin_amdgcn_mfma_f32_16x16x32_bf16(
                        vf, pf[kst][n], o[md][n], 0, 0, 0);
            }
    }

    // per-row m,l for the combine
    if (quad == 0) {
        #pragma unroll
        for (int n = 0; n < 2; ++n) {
            int row = b * ROWS_Q + q0 + n * 16 + c;
            mbuf[(part * 4 + h) * MQ + row] = m_i[n];
            lbuf[(part * 4 + h) * MQ + row] = l_i[n];
        }
    }

    __syncthreads();
    bf16* Osh = (bf16*)smem + wave * (32 * 136);
    float inv[2] = {1.0f / l_i[0], 1.0f / l_i[1]};
    #pragma unroll
    for (int md = 0; md < 8; ++md)
        #pragma unroll
        for (int n = 0; n < 2; ++n)
            #pragma unroll
            for (int hh = 0; hh < 2; ++hh) {
                u32 w = pack_bf16(o[md][n][2 * hh] * inv[n], o[md][n][2 * hh + 1] * inv[n]);
                int d = md * 16 + quad * 4 + 2 * hh;
                int qq = n * 16 + c;
                *(u32*)(Osh + qq * 136 + d) = w;
            }
    __syncthreads();
    bf16* opb = part ? op1 : op0;
    bf16* og = opb + (size_t)(b * ROWS_Q + q0) * HID + h * HD;
    #pragma unroll
    for (int i = 0; i < 8; ++i) {
        int idx = i * 64 + lane;
        int qq = idx >> 4;
        int ch = idx & 15;
        bf16x8 vv = *(const bf16x8*)(Osh + qq * 136 + ch * 8);
        *(bf16x8*)(og + (size_t)qq * HID + ch * 8) = vv;
    }
}

// Combine the two normalized KV-half partials: out = w1*o1 + w2*o2.
__global__ __launch_bounds__(256) void comb_kernel(
    const bf16* __restrict__ o0, const bf16* __restrict__ o1,
    const float* __restrict__ mbuf, const float* __restrict__ lbuf,
    bf16* __restrict__ outb)
{
    int idx = blockIdx.x * 256 + threadIdx.x;   // MQ*64 groups of 8 bf16
    int row = idx >> 6;
    int col8 = idx & 63;
    int h = col8 >> 4;
    int mli = h * MQ + row;
    float m1 = mbuf[mli],          l1 = lbuf[mli];
    float m2 = mbuf[4 * MQ + mli], l2 = lbuf[4 * MQ + mli];
    float mm = fmaxf(m1, m2);
    float a1 = l1 * __expf(m1 - mm), a2 = l2 * __expf(m2 - mm);
    float inv = 1.0f / (a1 + a2);
    float w1 = a1 * inv, w2 = a2 * inv;
    size_t off = (size_t)idx * 8;
    bf16x8 v1 = *(const bf16x8*)(o0 + off);
    bf16x8 v2 = *(const bf16x8*)(o1 + off);
    bf16x8 r;
    #pragma unroll
    for (int j = 0; j < 8; ++j)
        r[j] = (bf16)((float)v1[j] * w1 + (float)v2[j] * w2);
    *(bf16x8*)(outb + off) = r;
}

extern "C" void kernel_launch(void* const* d_in, const int* in_sizes, int n_in,
                              void* d_out, int out_size, void* d_ws, size_t ws_size,
                              hipStream_t stream)
{
    const float* x     = (const float*)d_in[0];
    const float* slow  = (const float*)d_in[1];
    const float* Wq_in = (const float*)d_in[3];
    const float* bq_in = (const float*)d_in[4];
    const float* Wm    = (const float*)d_in[5];
    const float* bm    = (const float*)d_in[6];
    const float* Wq    = (const float*)d_in[7];
    const float* bq    = (const float*)d_in[8];
    const float* Wk    = (const float*)d_in[9];
    const float* bk    = (const float*)d_in[10];
    const float* Wv    = (const float*)d_in[11];
    const float* bv    = (const float*)d_in[12];
    const float* Wo    = (const float*)d_in[13];
    const float* bo    = (const float*)d_in[14];
    const float* g1    = (const float*)d_in[15];
    const float* be1   = (const float*)d_in[16];
    const float* W1    = (const float*)d_in[17];
    const float* b1    = (const float*)d_in[18];
    const float* W2    = (const float*)d_in[19];
    const float* b2    = (const float*)d_in[20];
    const float* g2    = (const float*)d_in[21];
    const float* be2   = (const float*)d_in[22];
    const float* M1    = (const float*)d_in[23];
    const float* bm1   = (const float*)d_in[24];
    const float* M2    = (const float*)d_in[25];
    const float* bm2   = (const float*)d_in[26];
    float* out = (float*)d_out;

    // ---- workspace layout ----
    float* q_in_f = (float*)d_ws;                         // MQ*512 f32
    float* ob     = q_in_f + (size_t)MQ * HID;            // MQ*512 f32
    float* bkv    = ob + (size_t)MQ * HID;                // 1024 f32
    bf16* shared_b = (bf16*)(bkv + 1024);                 // MQ*1024 (slow_b/attn_b/ff1_b/m1_b)
    bf16* q_in_b = shared_b + (size_t)MQ * FF;            // MQ*512
    bf16* kv_b   = q_in_b + (size_t)MQ * HID;             // MK*1024
    bf16* h_b    = kv_b + (size_t)MK * EMB;               // MQ*512
    bf16* q16    = h_b + (size_t)MQ * HID;                // MQ*512
    bf16* kv16   = q16 + (size_t)MQ * HID;                // MK*1024 (k|v fused)
    bf16* qbt    = kv16 + (size_t)MK * EMB;               // MQ*512
    bf16* kbt    = qbt + (size_t)MQ * HID;                // MK*512
    bf16* Vt     = kbt + (size_t)MK * HID;                // 8*128*2048
    bf16* Wq_in_t = Vt + (size_t)8 * HD * ROWS_K;         // 512*896
    bf16* Wq_t  = Wq_in_t + 512 * 896;                    // 512*512
    bf16* kvw_t = Wq_t + 512 * 512;                       // 1024*1024 (Wk_t | Wv_t)
    bf16* Wo_t  = kvw_t + 1024 * 1024;                    // 512*512
    bf16* W1_t  = Wo_t + 512 * 512;                       // 1024*512
    bf16* W2_t  = W1_t + 1024 * 512;                      // 512*1024
    bf16* M1_t  = W2_t + 512 * 1024;                      // 1024*512
    bf16* M2_t  = M1_t + 1024 * 512;                      // 896*1024
    bf16* slow_b = shared_b;
    bf16* attn_b = shared_b;
    bf16* ff1_b  = shared_b;
    bf16* m1_b   = shared_b;

    // attention partial buffers: reuse regions dead by the time mattn runs
    bf16* opart0 = q16;               // dead after rope(q16 -> qbt)
    bf16* opart1 = q_in_b;            // dead after q-projection GEMM
    float* mlm   = (float*)kv16;      // dead after rope(k) + vt_tiled; 8*MQ f32
    float* mll   = mlm + 8 * MQ;      //                                8*MQ f32

    dim3 blk(256);

    // ---- all weight transposes in one launch ----
    TDescs td;
    int t0 = 0;
    auto set = [&](int i, const float* s, bf16* d, int K, int N) {
        td.d[i] = {s, d, K, N, t0};
        t0 += (N / 32) * (K / 32);
    };
    set(0, Wq_in, Wq_in_t, 896, 512);
    set(1, Wq,    Wq_t,    512, 512);
    set(2, Wk,    kvw_t,              1024, 512);
    set(3, Wv,    kvw_t + 512 * 1024, 1024, 512);
    set(4, Wo,    Wo_t,    512, 512);
    set(5, W1,    W1_t,    512, 1024);
    set(6, W2,    W2_t,    1024, 512);
    set(7, M1,    M1_t,    512, 1024);
    set(8, M2,    M2_t,    1024, 896);
    transpose_all<<<t0, blk, 0, stream>>>(td);

    // bias concat for fused KV GEMM
    hipMemcpyAsync(bkv,       bk, 512 * sizeof(float), hipMemcpyDeviceToDevice, stream);
    hipMemcpyAsync(bkv + 512, bv, 512 * sizeof(float), hipMemcpyDeviceToDevice, stream);

    cvt_kernel<<<(MQ * DQ / 4 + 255) / 256, blk, 0, stream>>>(slow, slow_b, MQ * DQ / 4);
    kv_kernel<<<(MK * EMB) / 256, blk, 0, stream>>>(x, Wm, bm, kv_b);

    // q_in = slow @ Wq_in + bq_in -> fp32 (residual) + bf16   grid 4x196
    mgemm64<OP_BIAS, true, true><<<dim3(4, 196), blk, 0, stream>>>(
        slow_b, Wq_in_t, bq_in, nullptr, q_in_f, q_in_b, MQ, HID, DQ);
    // q projection -> bf16   grid 4x196
    mgemm64<OP_BIAS, false, true><<<dim3(4, 196), blk, 0, stream>>>(
        q_in_b, Wq_t, bq, nullptr, nullptr, q16, MQ, HID, HID);
    // fused k|v projection -> kv16 (MK x 1024)   grid 8x64
    mgemm64<OP_BIAS, false, true><<<dim3(8, 64), blk, 0, stream>>>(
        kv_b, kvw_t, bkv, nullptr, nullptr, kv16, MK, 1024, EMB);
    // RoPE (q pre-scaled by 1/sqrt(128)); k read from fused kv16
    rope_b_kernel<<<(MQ * 128 + 255) / 256, blk, 0, stream>>>(
        q16, qbt, ROWS_Q, 196, 14, MQ * 128, 0.08838834764831843f, 512, 0);
    rope_b_kernel<<<(MK * 128 + 255) / 256, blk, 0, stream>>>(
        kv16, kbt, ROWS_K, 64, 8, MK * 128, 1.0f, 1024, 0);
    // V transpose (coalesced)
    vt_tiled<<<dim3(32, 2, 8), blk, 0, stream>>>(kv16, Vt);
    // MFMA flash attention, KV-split-2: grid 784 partials + combine
    mattn_kernel<<<dim3(784), blk, 0, stream>>>(qbt, kbt, Vt, opart0, opart1, mlm, mll);
    comb_kernel<<<dim3(MQ * 64 / 256), blk, 0, stream>>>(opart0, opart1, mlm, mll, attn_b);
    // pre_ln = attn @ Wo + bo + q_in   grid 4x196
    mgemm64<OP_RES, true, false><<<dim3(4, 196), blk, 0, stream>>>(
        attn_b, Wo_t, bo, q_in_f, ob, nullptr, MQ, HID, HID);
    ln_kernel<<<MQ / 4, blk, 0, stream>>>(ob, g1, be1, h_b);
    // ff1 = gelu(h @ W1 + b1)   grid 8x98 (128-tile)
    mgemm<OP_GELU, false, true><<<dim3(8, 98), blk, 0, stream>>>(
        h_b, W1_t, b1, nullptr, nullptr, ff1_b, MQ, FF, HID);
    // pre2 = ff1 @ W2 + b2 + h   grid 4x196
    mgemm64<OP_RES, true, false><<<dim3(4, 196), blk, 0, stream>>>(
        ff1_b, W2_t, b2, ob, q_in_f, nullptr, MQ, HID, FF);
    ln_kernel<<<MQ / 4, blk, 0, stream>>>(q_in_f, g2, be2, h_b);
    // m1 = gelu(h2 @ M1 + bm1)   grid 8x98
    mgemm<OP_GELU, false, true><<<dim3(8, 98), blk, 0, stream>>>(
        h_b, M1_t, bm1, nullptr, nullptr, m1_b, MQ, 2 * HID, HID);
    // out = m1 @ M2 + bm2   grid 7x98
    mgemm<OP_BIAS, true, false><<<dim3(7, 98), blk, 0, stream>>>(
        m1_b, M2_t, bm2, nullptr, out, nullptr, MQ, OUTD, 2 * HID);
}

// Round 7
// 569.916 us; speedup vs baseline: 1.4121x; 1.0279x over previous
//
#include <hip/hip_runtime.h>
#include <cstdint>
#include <cstddef>

// ---------------- dims ----------------
#define BATCH 2
#define MQ 12544          // B * TQ * NQ
#define ROWS_Q 6272
#define MK 4096           // B * T*H*W
#define ROWS_K 2048
#define HID 512
#define NH 4
#define HD 128
#define EMB 1024
#define DQ 896
#define FF 1024
#define OUTD 896

typedef __bf16 bf16;
typedef unsigned int u32;
typedef bf16 bf16x8 __attribute__((ext_vector_type(8)));
typedef bf16 bf16x4 __attribute__((ext_vector_type(4)));
typedef float f32x4 __attribute__((ext_vector_type(4)));

enum { OP_BIAS = 0, OP_GELU = 1, OP_RES = 2 };

__device__ __forceinline__ float gelu_tanh(float x) {
    float x3 = x * x * x;
    return 0.5f * x * (1.0f + tanhf(0.7978845608028654f * (x + 0.044715f * x3)));
}

__device__ __forceinline__ void gld16(const bf16* g, bf16* l) {
    __builtin_amdgcn_global_load_lds(
        (const __attribute__((address_space(1))) unsigned int*)g,
        (__attribute__((address_space(3))) unsigned int*)l, 16, 0, 0);
}

__device__ __forceinline__ u32 pack_bf16(float a, float b) {
    union { bf16 h[2]; u32 w; } u;
    u.h[0] = (bf16)a; u.h[1] = (bf16)b;
    return u.w;
}

// ---------------------------------------------------------------------------
// bf16 MFMA GEMM, 128x128 tile, BK=64 (2x BK=32 phases per barrier pair).
// Round-7: the BK=32 loop paid 2 barriers + full vmcnt drain per 32 of K
// with only 16 MFMA to amortize; unroll x2 via a SECOND identical LDS buffer
// pair (same 64B row pitch -> same bank pattern, same gld16-linear dests,
// same K accumulation order -> bitwise-identical results). LDS 32 KB.
// ---------------------------------------------------------------------------
template <int OP, bool WF32, bool WB16>
__global__ __launch_bounds__(256) void mgemm(
    const bf16* __restrict__ A, const bf16* __restrict__ Bt,
    const float* __restrict__ bias, const float* __restrict__ res,
    float* __restrict__ Cf, bf16* __restrict__ Cb, int M, int N, int K)
{
    __shared__ __align__(16) bf16 As0[128 * 32];
    __shared__ __align__(16) bf16 As1[128 * 32];
    __shared__ __align__(16) bf16 Bs0[128 * 32];
    __shared__ __align__(16) bf16 Bs1[128 * 32];
    const int tid  = threadIdx.x;
    const int m0   = blockIdx.y * 128;
    const int n0   = blockIdx.x * 128;
    const int wave = tid >> 6, lane = tid & 63;
    const int wm = (wave >> 1) * 64, wn = (wave & 1) * 64;

    f32x4 acc[4][4] = {};

    const int srow = tid >> 2;
    const int scol = (tid & 3) * 8;
    const bf16* Ag = A  + (size_t)(m0 + srow) * K + scol;
    const bf16* Bg = Bt + (size_t)(n0 + srow) * K + scol;
    bf16* Al0 = &As0[tid * 8];
    bf16* Al1 = &As1[tid * 8];
    bf16* Bl0 = &Bs0[tid * 8];
    bf16* Bl1 = &Bs1[tid * 8];
    const size_t half = (size_t)64 * K;

    const int fr = lane & 15;
    const int kq = (lane >> 4) * 8;
    const bf16* pa0 = &As0[(wm + fr) * 32 + kq];
    const bf16* pa1 = &As1[(wm + fr) * 32 + kq];
    const bf16* pb0 = &Bs0[(wn + fr) * 32 + kq];
    const bf16* pb1 = &Bs1[(wn + fr) * 32 + kq];

    for (int k0 = 0; k0 < K; k0 += 64) {
        gld16(Ag + k0,             Al0);
        gld16(Ag + k0 + half,      Al0 + 64 * 32);
        gld16(Bg + k0,             Bl0);
        gld16(Bg + k0 + half,      Bl0 + 64 * 32);
        gld16(Ag + k0 + 32,        Al1);
        gld16(Ag + k0 + 32 + half, Al1 + 64 * 32);
        gld16(Bg + k0 + 32,        Bl1);
        gld16(Bg + k0 + 32 + half, Bl1 + 64 * 32);
        __syncthreads();

        {
            bf16x8 af[4], bfr[4];
            #pragma unroll
            for (int i = 0; i < 4; ++i) af[i]  = *(const bf16x8*)(pa0 + i * 16 * 32);
            #pragma unroll
            for (int j = 0; j < 4; ++j) bfr[j] = *(const bf16x8*)(pb0 + j * 16 * 32);
            #pragma unroll
            for (int i = 0; i < 4; ++i)
                #pragma unroll
                for (int j = 0; j < 4; ++j)
                    acc[i][j] = __builtin_amdgcn_mfma_f32_16x16x32_bf16(
                        af[i], bfr[j], acc[i][j], 0, 0, 0);
        }
        {
            bf16x8 af[4], bfr[4];
            #pragma unroll
            for (int i = 0; i < 4; ++i) af[i]  = *(const bf16x8*)(pa1 + i * 16 * 32);
            #pragma unroll
            for (int j = 0; j < 4; ++j) bfr[j] = *(const bf16x8*)(pb1 + j * 16 * 32);
            #pragma unroll
            for (int i = 0; i < 4; ++i)
                #pragma unroll
                for (int j = 0; j < 4; ++j)
                    acc[i][j] = __builtin_amdgcn_mfma_f32_16x16x32_bf16(
                        af[i], bfr[j], acc[i][j], 0, 0, 0);
        }
        __syncthreads();
    }

    const int colb = n0 + wn + (lane & 15);
    const int rowb = m0 + wm + (lane >> 4) * 4;
    #pragma unroll
    for (int i = 0; i < 4; ++i) {
        #pragma unroll
        for (int j = 0; j < 4; ++j) {
            const int c = colb + j * 16;
            const float bj = bias[c];
            #pragma unroll
            for (int r = 0; r < 4; ++r) {
                const int m = rowb + i * 16 + r;
                float v = acc[i][j][r] + bj;
                if (OP == OP_GELU) v = gelu_tanh(v);
                if (OP == OP_RES)  v += res[(size_t)m * N + c];
                if (WF32) Cf[(size_t)m * N + c] = v;
                if (WB16) Cb[(size_t)m * N + c] = (bf16)v;
            }
        }
    }
}

// ---------------------------------------------------------------------------
// bf16 MFMA GEMM, 64x128 tile, BK=64 (2x BK=32 phases per barrier pair).
// Same unroll rationale as mgemm. LDS 24 KB.
// ---------------------------------------------------------------------------
template <int OP, bool WF32, bool WB16>
__global__ __launch_bounds__(256) void mgemm64(
    const bf16* __restrict__ A, const bf16* __restrict__ Bt,
    const float* __restrict__ bias, const float* __restrict__ res,
    float* __restrict__ Cf, bf16* __restrict__ Cb, int M, int N, int K)
{
    __shared__ __align__(16) bf16 As0[64 * 32];
    __shared__ __align__(16) bf16 As1[64 * 32];
    __shared__ __align__(16) bf16 Bs0[128 * 32];
    __shared__ __align__(16) bf16 Bs1[128 * 32];
    const int tid  = threadIdx.x;
    const int m0   = blockIdx.y * 64;
    const int n0   = blockIdx.x * 128;
    const int wave = tid >> 6, lane = tid & 63;
    const int wm = (wave >> 1) * 32, wn = (wave & 1) * 64;

    f32x4 acc[2][4] = {};

    const int srow = tid >> 2;
    const int scol = (tid & 3) * 8;
    const bf16* Ag = A  + (size_t)(m0 + srow) * K + scol;
    const bf16* Bg = Bt + (size_t)(n0 + srow) * K + scol;
    bf16* Al0 = &As0[tid * 8];
    bf16* Al1 = &As1[tid * 8];
    bf16* Bl0 = &Bs0[tid * 8];
    bf16* Bl1 = &Bs1[tid * 8];
    const size_t half = (size_t)64 * K;

    const int fr = lane & 15;
    const int kq = (lane >> 4) * 8;
    const bf16* pa0 = &As0[(wm + fr) * 32 + kq];
    const bf16* pa1 = &As1[(wm + fr) * 32 + kq];
    const bf16* pb0 = &Bs0[(wn + fr) * 32 + kq];
    const bf16* pb1 = &Bs1[(wn + fr) * 32 + kq];

    for (int k0 = 0; k0 < K; k0 += 64) {
        gld16(Ag + k0,             Al0);
        gld16(Bg + k0,             Bl0);
        gld16(Bg + k0 + half,      Bl0 + 64 * 32);
        gld16(Ag + k0 + 32,        Al1);
        gld16(Bg + k0 + 32,        Bl1);
        gld16(Bg + k0 + 32 + half, Bl1 + 64 * 32);
        __syncthreads();

        {
            bf16x8 af[2], bfr[4];
            #pragma unroll
            for (int i = 0; i < 2; ++i) af[i]  = *(const bf16x8*)(pa0 + i * 16 * 32);
            #pragma unroll
            for (int j = 0; j < 4; ++j) bfr[j] = *(const bf16x8*)(pb0 + j * 16 * 32);
            #pragma unroll
            for (int i = 0; i < 2; ++i)
                #pragma unroll
                for (int j = 0; j < 4; ++j)
                    acc[i][j] = __builtin_amdgcn_mfma_f32_16x16x32_bf16(
                        af[i], bfr[j], acc[i][j], 0, 0, 0);
        }
        {
            bf16x8 af[2], bfr[4];
            #pragma unroll
            for (int i = 0; i < 2; ++i) af[i]  = *(const bf16x8*)(pa1 + i * 16 * 32);
            #pragma unroll
            for (int j = 0; j < 4; ++j) bfr[j] = *(const bf16x8*)(pb1 + j * 16 * 32);
            #pragma unroll
            for (int i = 0; i < 2; ++i)
                #pragma unroll
                for (int j = 0; j < 4; ++j)
                    acc[i][j] = __builtin_amdgcn_mfma_f32_16x16x32_bf16(
                        af[i], bfr[j], acc[i][j], 0, 0, 0);
        }
        __syncthreads();
    }

    const int colb = n0 + wn + (lane & 15);
    const int rowb = m0 + wm + (lane >> 4) * 4;
    #pragma unroll
    for (int i = 0; i < 2; ++i) {
        #pragma unroll
        for (int j = 0; j < 4; ++j) {
            const int c = colb + j * 16;
            const float bj = bias[c];
            #pragma unroll
            for (int r = 0; r < 4; ++r) {
                const int m = rowb + i * 16 + r;
                float v = acc[i][j][r] + bj;
                if (OP == OP_GELU) v = gelu_tanh(v);
                if (OP == OP_RES)  v += res[(size_t)m * N + c];
                if (WF32) Cf[(size_t)m * N + c] = v;
                if (WB16) Cb[(size_t)m * N + c] = (bf16)v;
            }
        }
    }
}

// ---------------------------------------------------------------------------
// All 9 weight transposes (fp32 KxN -> bf16 NxK) in ONE launch.
// ---------------------------------------------------------------------------
struct TDesc { const float* src; bf16* dst; int K; int N; int tile0; };
struct TDescs { TDesc d[9]; };

__global__ __launch_bounds__(256) void transpose_all(TDescs td)
{
    __shared__ float t[32][33];
    const int blk = blockIdx.x;
    int i = 0;
    #pragma unroll
    for (int j = 1; j < 9; ++j) if (blk >= td.d[j].tile0) i = j;
    const float* src = td.d[i].src;
    bf16* dst = td.d[i].dst;
    const int K = td.d[i].K, N = td.d[i].N;
    const int local = blk - td.d[i].tile0;
    const int ntx = N >> 5;
    const int bx = local % ntx, by = local / ntx;
    const int x = threadIdx.x & 31, y = threadIdx.x >> 5;
    #pragma unroll
    for (int p = 0; p < 32; p += 8)
        t[y + p][x] = src[(size_t)(by * 32 + y + p) * N + bx * 32 + x];
    __syncthreads();
    #pragma unroll
    for (int p = 0; p < 32; p += 8)
        dst[(size_t)(bx * 32 + y + p) * K + by * 32 + x] = (bf16)t[x][y + p];
}

// fp32 -> bf16 elementwise
__global__ __launch_bounds__(256) void cvt_kernel(
    const float* __restrict__ in, bf16* __restrict__ out, int n4)
{
    int i = blockIdx.x * 256 + threadIdx.x;
    if (i >= n4) return;
    float4 v = ((const float4*)in)[i];
    out[4 * i + 0] = (bf16)v.x;
    out[4 * i + 1] = (bf16)v.y;
    out[4 * i + 2] = (bf16)v.z;
    out[4 * i + 3] = (bf16)v.w;
}

// kv = x @ Wm + bm  (K=4), bf16 out.
__global__ __launch_bounds__(256) void kv_kernel(
    const float* __restrict__ x, const float* __restrict__ Wm,
    const float* __restrict__ bm, bf16* __restrict__ kv)
{
    int idx = blockIdx.x * 256 + threadIdx.x;
    int r = idx >> 10, n = idx & 1023;
    float4 xv = *(const float4*)(x + (size_t)r * 4);
    float v = bm[n] + xv.x * Wm[n] + xv.y * Wm[1024 + n]
                    + xv.z * Wm[2048 + n] + xv.w * Wm[3072 + n];
    kv[idx] = (bf16)v;
}

// 3D RoPE: bf16 in (row stride istr, col offset icoff) -> bf16 out (rows x 512).
__global__ __launch_bounds__(256) void rope_b_kernel(
    const bf16* __restrict__ in, bf16* __restrict__ out,
    int tok, int gdiv, int wdiv, int total, float sc, int istr, int icoff)
{
    int idx = blockIdx.x * 256 + threadIdx.x;
    if (idx >= total) return;
    int row = idx >> 7;
    int r2 = idx & 127;
    int h = r2 >> 5;
    int j2 = r2 & 31;
    int j = 2 * j2;
    int n = row % tok;
    int t = n / gdiv;
    int g = n % gdiv;
    int gh = g / wdiv;
    int gw = g % wdiv;
    float pa = (j < 22) ? (float)t : (j < 43) ? (float)gh : (float)gw;
    int j1 = j + 1;
    float pb = (j1 < 22) ? (float)t : (j1 < 43) ? (float)gh : (float)gw;
    float fra = pa * exp2f(-(float)j  * 0.20762050593045954f);
    float frb = pb * exp2f(-(float)j1 * 0.20762050593045954f);
    float ca = cosf(fra), sa = sinf(fra);
    float cb = cosf(frb), sb = sinf(frb);
    size_t ibase = (size_t)row * istr + icoff + (size_t)h * 128 + j;
    size_t obase = (size_t)row * 512 + (size_t)h * 128 + j;
    union { u32 w; bf16 e[2]; } ua, ub;
    ua.w = *(const u32*)(in + ibase);
    ub.w = *(const u32*)(in + ibase + 64);
    float x1a = (float)ua.e[0], x1b = (float)ua.e[1];
    float x2a = (float)ub.e[0], x2b = (float)ub.e[1];
    *(u32*)(out + obase)      = pack_bf16((x1a * ca - x2a * sa) * sc,
                                          (x1b * cb - x2b * sb) * sc);
    *(u32*)(out + obase + 64) = pack_bf16((x2a * ca + x1a * sa) * sc,
                                          (x2b * cb + x1b * sb) * sc);
}

// Coalesced V transpose: kv16[t][512 + h*128 + d] -> Vt[b][h][d][2048]
__global__ __launch_bounds__(256) void vt_tiled(
    const bf16* __restrict__ kv16, bf16* __restrict__ vt)
{
    __shared__ bf16 t[64][72];
    const int tt = blockIdx.x * 64;
    const int d0 = blockIdx.y * 64;
    const int bh = blockIdx.z;
    const int b = bh >> 2, h = bh & 3;
    const int rr = threadIdx.x >> 4;
    const int cc = (threadIdx.x & 15) * 4;
    #pragma unroll
    for (int p = 0; p < 4; ++p) {
        int r = rr + p * 16;
        *(bf16x4*)&t[r][cc] = *(const bf16x4*)
            (kv16 + (size_t)(b * ROWS_K + tt + r) * 1024 + 512 + h * 128 + d0 + cc);
    }
    __syncthreads();
    #pragma unroll
    for (int p = 0; p < 4; ++p) {
        int r = rr + p * 16;   // d-local
        bf16x4 v;
        v[0] = t[cc + 0][r]; v[1] = t[cc + 1][r];
        v[2] = t[cc + 2][r]; v[3] = t[cc + 3][r];
        *(bf16x4*)(vt + (size_t)bh * HD * ROWS_K + (size_t)(d0 + r) * ROWS_K + tt + cc) = v;
    }
}

// LayerNorm in-place on (rows x 512) + bf16 copy.
__global__ __launch_bounds__(256) void ln_kernel(
    float* __restrict__ xb, const float* __restrict__ g,
    const float* __restrict__ be, bf16* __restrict__ out16)
{
    int wave = threadIdx.x >> 6, lane = threadIdx.x & 63;
    size_t row = (size_t)blockIdx.x * 4 + wave;
    float* xp = xb + row * 512;
    float4 a = ((const float4*)xp)[lane];
    float4 b = ((const float4*)xp)[lane + 64];
    float s  = a.x + a.y + a.z + a.w + b.x + b.y + b.z + b.w;
    float sq = a.x*a.x + a.y*a.y + a.z*a.z + a.w*a.w
             + b.x*b.x + b.y*b.y + b.z*b.z + b.w*b.w;
    #pragma unroll
    for (int off = 32; off; off >>= 1) {
        s  += __shfl_xor(s, off);
        sq += __shfl_xor(sq, off);
    }
    float mean = s * (1.0f / 512.0f);
    float var  = sq * (1.0f / 512.0f) - mean * mean;
    float rstd = rsqrtf(var + 1e-5f);
    float4 gv1 = ((const float4*)g)[lane],  gv2 = ((const float4*)g)[lane + 64];
    float4 bv1 = ((const float4*)be)[lane], bv2 = ((const float4*)be)[lane + 64];
    a.x = (a.x - mean) * rstd * gv1.x + bv1.x;
    a.y = (a.y - mean) * rstd * gv1.y + bv1.y;
    a.z = (a.z - mean) * rstd * gv1.z + bv1.z;
    a.w = (a.w - mean) * rstd * gv1.w + bv1.w;
    b.x = (b.x - mean) * rstd * gv2.x + bv2.x;
    b.y = (b.y - mean) * rstd * gv2.y + bv2.y;
    b.z = (b.z - mean) * rstd * gv2.z + bv2.z;
    b.w = (b.w - mean) * rstd * gv2.w + bv2.w;
    ((float4*)xp)[lane]      = a;
    ((float4*)xp)[lane + 64] = b;
    bf16* op = out16 + row * 512;
    *(u32*)(op + lane * 4)       = pack_bf16(a.x, a.y);
    *(u32*)(op + lane * 4 + 2)   = pack_bf16(a.z, a.w);
    *(u32*)(op + 256 + lane * 4)     = pack_bf16(b.x, b.y);
    *(u32*)(op + 256 + lane * 4 + 2) = pack_bf16(b.z, b.w);
}

// ---------------------------------------------------------------------------
// MFMA flash attention (bf16, fp32 accum) — VERBATIM round-0 body and strides
// (136/72/136; R5 proved padded strides 140/76 were the rounds-1..5 3x
// regression: 8-mod-16-byte row pitch -> misaligned ds_*_b128 slow path).
// R6 A/B (392x32 vs 784x16 tiles: 121.1 vs 120.2us) proved the kernel is at
// its register-structure's per-CU throughput limit -- residency ~1 block/CU
// (128 arch VGPR + ~100 acc regs > 256/wave), so grid/split changes are
// neutral and per-wave restructures break regalloc (rounds 1-4). Single-pass
// again (no split/comb: comb cost ~7us for zero gain).
// Only delta vs round 0: XCD swizzle bid remap (bh=bid&7, qt=bid>>3) --
// R5-proven codegen-safe (VGPR stayed 128) and FETCH 39->10 MB (K/V staging
// becomes XCD-local L2 hits, trimming exposed staging latency).
// ---------------------------------------------------------------------------
__global__ __launch_bounds__(256, 2) void mattn_kernel(
    const bf16* __restrict__ qs, const bf16* __restrict__ ks,
    const bf16* __restrict__ vt, bf16* __restrict__ outb)
{
    __shared__ __align__(16) char smem[35840];
    bf16* Ksh = (bf16*)smem;            // [64][136]
    bf16* Vsh = (bf16*)(smem + 17408);  // [128][72]

    const int tid = threadIdx.x;
    const int wave = tid >> 6, lane = tid & 63;
    const int quad = lane >> 4, c = lane & 15;
    const int bid = blockIdx.x;
    const int bh = bid & 7;             // XCD-locality: same (b,h) -> same XCD
    const int qt = bid >> 3;
    const int h  = bh & 3;
    const int b  = bh >> 2;

    const int q0 = qt * 128 + wave * 32;
    const bf16* qg = qs + (size_t)(b * ROWS_Q + q0) * HID + h * HD;
    const bf16* kg = ks + (size_t)(b * ROWS_K) * HID + h * HD;
    const bf16* vg = vt + (size_t)(b * NH + h) * HD * ROWS_K;

    bf16x8 qf[2][4];
    #pragma unroll
    for (int n = 0; n < 2; ++n)
        #pragma unroll
        for (int s = 0; s < 4; ++s)
            qf[n][s] = *(const bf16x8*)(qg + (size_t)(n * 16 + c) * HID + s * 32 + quad * 8);

    f32x4 o[8][2] = {};
    float m_i[2] = {-1e30f, -1e30f}, l_i[2] = {0.0f, 0.0f};

    const int st_t = tid >> 2;
    const int st_d = (tid & 3) * 32;
    const int sv_d = tid >> 1;
    const int sv_t = (tid & 1) * 32;

    for (int kt = 0; kt < 32; ++kt) {
        __syncthreads();
        {
            const bf16* src = kg + (size_t)(kt * 64 + st_t) * HID + st_d;
            bf16* dst = Ksh + st_t * 136 + st_d;
            #pragma unroll
            for (int i = 0; i < 4; ++i)
                *(bf16x8*)(dst + i * 8) = *(const bf16x8*)(src + i * 8);
        }
        {
            const bf16* src = vg + (size_t)sv_d * ROWS_K + kt * 64 + sv_t;
            bf16* dst = Vsh + sv_d * 72 + sv_t;
            #pragma unroll
            for (int i = 0; i < 4; ++i)
                *(bf16x8*)(dst + i * 8) = *(const bf16x8*)(src + i * 8);
        }
        __syncthreads();

        f32x4 s[4][2] = {};
        #pragma unroll
        for (int ksi = 0; ksi < 4; ++ksi) {
            bf16x8 kf[4];
            #pragma unroll
            for (int mi = 0; mi < 4; ++mi)
                kf[mi] = *(const bf16x8*)(Ksh + (mi * 16 + c) * 136 + ksi * 32 + quad * 8);
            #pragma unroll
            for (int mi = 0; mi < 4; ++mi)
                #pragma unroll
                for (int n = 0; n < 2; ++n)
                    s[mi][n] = __builtin_amdgcn_mfma_f32_16x16x32_bf16(
                        kf[mi], qf[n][ksi], s[mi][n], 0, 0, 0);
        }

        float alpha[2];
        #pragma unroll
        for (int n = 0; n < 2; ++n) {
            float mx = -1e30f;
            #pragma unroll
            for (int mi = 0; mi < 4; ++mi)
                #pragma unroll
                for (int r = 0; r < 4; ++r) mx = fmaxf(mx, s[mi][n][r]);
            mx = fmaxf(mx, __shfl_xor(mx, 16));
            mx = fmaxf(mx, __shfl_xor(mx, 32));
            float mn = fmaxf(m_i[n], mx);
            alpha[n] = __expf(m_i[n] - mn);
            m_i[n] = mn;
            float sm = 0.0f;
            #pragma unroll
            for (int mi = 0; mi < 4; ++mi)
                #pragma unroll
                for (int r = 0; r < 4; ++r) {
                    float p = __expf(s[mi][n][r] - mn);
                    s[mi][n][r] = p;
                    sm += p;
                }
            sm += __shfl_xor(sm, 16);
            sm += __shfl_xor(sm, 32);
            l_i[n] = l_i[n] * alpha[n] + sm;
            #pragma unroll
            for (int md = 0; md < 8; ++md) {
                o[md][n][0] *= alpha[n]; o[md][n][1] *= alpha[n];
                o[md][n][2] *= alpha[n]; o[md][n][3] *= alpha[n];
            }
        }

        u32 pk[4][2][2];
        #pragma unroll
        for (int mi = 0; mi < 4; ++mi)
            #pragma unroll
            for (int n = 0; n < 2; ++n) {
                pk[mi][n][0] = pack_bf16(s[mi][n][0], s[mi][n][1]);
                pk[mi][n][1] = pack_bf16(s[mi][n][2], s[mi][n][3]);
            }
        bf16x8 pf[2][2];
        #pragma unroll
        for (int kst = 0; kst < 2; ++kst)
            #pragma unroll
            for (int n = 0; n < 2; ++n) {
                union { bf16x8 v8; u32 d[4]; } u;
                #pragma unroll
                for (int dw = 0; dw < 4; ++dw) {
                    int srcl = ((quad & 1) * 2 + (dw >> 1)) * 16 + c;
                    u32 lo = (u32)__shfl((int)pk[2 * kst][n][dw & 1], srcl);
                    u32 hi = (u32)__shfl((int)pk[2 * kst + 1][n][dw & 1], srcl);
                    u.d[dw] = (quad >= 2) ? hi : lo;
                }
                pf[kst][n] = u.v8;
            }

        #pragma unroll
        for (int kst = 0; kst < 2; ++kst)
            #pragma unroll
            for (int md = 0; md < 8; ++md) {
                bf16x8 vf = *(const bf16x8*)(Vsh + (md * 16 + c) * 72 + kst * 32 + quad * 8);
                #pragma unroll
                for (int n = 0; n < 2; ++n)
                    o[md][n] = __builtin_amdgcn_mfma_f32_16x16x32_bf16(
                        vf, pf[kst][n], o[md][n], 0, 0, 0);
            }
    }

    __syncthreads();
    bf16* Osh = (bf16*)smem + wave * (32 * 136);
    float inv[2] = {1.0f / l_i[0], 1.0f / l_i[1]};
    #pragma unroll
    for (int md = 0; md < 8; ++md)
        #pragma unroll
        for (int n = 0; n < 2; ++n)
            #pragma unroll
            for (int hh = 0; hh < 2; ++hh) {
                u32 w = pack_bf16(o[md][n][2 * hh] * inv[n], o[md][n][2 * hh + 1] * inv[n]);
                int d = md * 16 + quad * 4 + 2 * hh;
                int qq = n * 16 + c;
                *(u32*)(Osh + qq * 136 + d) = w;
            }
    __syncthreads();
    bf16* og = outb + (size_t)(b * ROWS_Q + q0) * HID + h * HD;
    #pragma unroll
    for (int i = 0; i < 8; ++i) {
        int idx = i * 64 + lane;
        int qq = idx >> 4;
        int ch = idx & 15;
        bf16x8 vv = *(const bf16x8*)(Osh + qq * 136 + ch * 8);
        *(bf16x8*)(og + (size_t)qq * HID + ch * 8) = vv;
    }
}

extern "C" void kernel_launch(void* const* d_in, const int* in_sizes, int n_in,
                              void* d_out, int out_size, void* d_ws, size_t ws_size,
                              hipStream_t stream)
{
    const float* x     = (const float*)d_in[0];
    const float* slow  = (const float*)d_in[1];
    const float* Wq_in = (const float*)d_in[3];
    const float* bq_in = (const float*)d_in[4];
    const float* Wm    = (const float*)d_in[5];
    const float* bm    = (const float*)d_in[6];
    const float* Wq    = (const float*)d_in[7];
    const float* bq    = (const float*)d_in[8];
    const float* Wk    = (const float*)d_in[9];
    const float* bk    = (const float*)d_in[10];
    const float* Wv    = (const float*)d_in[11];
    const float* bv    = (const float*)d_in[12];
    const float* Wo    = (const float*)d_in[13];
    const float* bo    = (const float*)d_in[14];
    const float* g1    = (const float*)d_in[15];
    const float* be1   = (const float*)d_in[16];
    const float* W1    = (const float*)d_in[17];
    const float* b1    = (const float*)d_in[18];
    const float* W2    = (const float*)d_in[19];
    const float* b2    = (const float*)d_in[20];
    const float* g2    = (const float*)d_in[21];
    const float* be2   = (const float*)d_in[22];
    const float* M1    = (const float*)d_in[23];
    const float* bm1   = (const float*)d_in[24];
    const float* M2    = (const float*)d_in[25];
    const float* bm2   = (const float*)d_in[26];
    float* out = (float*)d_out;

    // ---- workspace layout ----
    float* q_in_f = (float*)d_ws;                         // MQ*512 f32
    float* ob     = q_in_f + (size_t)MQ * HID;            // MQ*512 f32
    float* bkv    = ob + (size_t)MQ * HID;                // 1024 f32
    bf16* shared_b = (bf16*)(bkv + 1024);                 // MQ*1024 (slow_b/attn_b/ff1_b/m1_b)
    bf16* q_in_b = shared_b + (size_t)MQ * FF;            // MQ*512
    bf16* kv_b   = q_in_b + (size_t)MQ * HID;             // MK*1024
    bf16* h_b    = kv_b + (size_t)MK * EMB;               // MQ*512
    bf16* q16    = h_b + (size_t)MQ * HID;                // MQ*512
    bf16* kv16   = q16 + (size_t)MQ * HID;                // MK*1024 (k|v fused)
    bf16* qbt    = kv16 + (size_t)MK * EMB;               // MQ*512
    bf16* kbt    = qbt + (size_t)MQ * HID;                // MK*512
    bf16* Vt     = kbt + (size_t)MK * HID;                // 8*128*2048
    bf16* Wq_in_t = Vt + (size_t)8 * HD * ROWS_K;         // 512*896
    bf16* Wq_t  = Wq_in_t + 512 * 896;                    // 512*512
    bf16* kvw_t = Wq_t + 512 * 512;                       // 1024*1024 (Wk_t | Wv_t)
    bf16* Wo_t  = kvw_t + 1024 * 1024;                    // 512*512
    bf16* W1_t  = Wo_t + 512 * 512;                       // 1024*512
    bf16* W2_t  = W1_t + 1024 * 512;                      // 512*1024
    bf16* M1_t  = W2_t + 512 * 1024;                      // 1024*512
    bf16* M2_t  = M1_t + 1024 * 512;                      // 896*1024
    bf16* slow_b = shared_b;
    bf16* attn_b = shared_b;
    bf16* ff1_b  = shared_b;
    bf16* m1_b   = shared_b;

    dim3 blk(256);

    // ---- all weight transposes in one launch ----
    TDescs td;
    int t0 = 0;
    auto set = [&](int i, const float* s, bf16* d, int K, int N) {
        td.d[i] = {s, d, K, N, t0};
        t0 += (N / 32) * (K / 32);
    };
    set(0, Wq_in, Wq_in_t, 896, 512);
    set(1, Wq,    Wq_t,    512, 512);
    set(2, Wk,    kvw_t,              1024, 512);
    set(3, Wv,    kvw_t + 512 * 1024, 1024, 512);
    set(4, Wo,    Wo_t,    512, 512);
    set(5, W1,    W1_t,    512, 1024);
    set(6, W2,    W2_t,    1024, 512);
    set(7, M1,    M1_t,    512, 1024);
    set(8, M2,    M2_t,    1024, 896);
    transpose_all<<<t0, blk, 0, stream>>>(td);

    // bias concat for fused KV GEMM
    hipMemcpyAsync(bkv,       bk, 512 * sizeof(float), hipMemcpyDeviceToDevice, stream);
    hipMemcpyAsync(bkv + 512, bv, 512 * sizeof(float), hipMemcpyDeviceToDevice, stream);

    cvt_kernel<<<(MQ * DQ / 4 + 255) / 256, blk, 0, stream>>>(slow, slow_b, MQ * DQ / 4);
    kv_kernel<<<(MK * EMB) / 256, blk, 0, stream>>>(x, Wm, bm, kv_b);

    // q_in = slow @ Wq_in + bq_in -> fp32 (residual) + bf16   grid 4x196
    mgemm64<OP_BIAS, true, true><<<dim3(4, 196), blk, 0, stream>>>(
        slow_b, Wq_in_t, bq_in, nullptr, q_in_f, q_in_b, MQ, HID, DQ);
    // q projection -> bf16   grid 4x196
    mgemm64<OP_BIAS, false, true><<<dim3(4, 196), blk, 0, stream>>>(
        q_in_b, Wq_t, bq, nullptr, nullptr, q16, MQ, HID, HID);
    // fused k|v projection -> kv16 (MK x 1024)   grid 8x64
    mgemm64<OP_BIAS, false, true><<<dim3(8, 64), blk, 0, stream>>>(
        kv_b, kvw_t, bkv, nullptr, nullptr, kv16, MK, 1024, EMB);
    // RoPE (q pre-scaled by 1/sqrt(128)); k read from fused kv16
    rope_b_kernel<<<(MQ * 128 + 255) / 256, blk, 0, stream>>>(
        q16, qbt, ROWS_Q, 196, 14, MQ * 128, 0.08838834764831843f, 512, 0);
    rope_b_kernel<<<(MK * 128 + 255) / 256, blk, 0, stream>>>(
        kv16, kbt, ROWS_K, 64, 8, MK * 128, 1.0f, 1024, 0);
    // V transpose (coalesced)
    vt_tiled<<<dim3(32, 2, 8), blk, 0, stream>>>(kv16, Vt);
    // MFMA flash attention -> attn_b (bf16), grid 392, XCD-swizzled
    mattn_kernel<<<dim3(392), blk, 0, stream>>>(qbt, kbt, Vt, attn_b);
    // pre_ln = attn @ Wo + bo + q_in   grid 4x196
    mgemm64<OP_RES, true, false><<<dim3(4, 196), blk, 0, stream>>>(
        attn_b, Wo_t, bo, q_in_f, ob, nullptr, MQ, HID, HID);
    ln_kernel<<<MQ / 4, blk, 0, stream>>>(ob, g1, be1, h_b);
    // ff1 = gelu(h @ W1 + b1)   grid 8x98 (128-tile)
    mgemm<OP_GELU, false, true><<<dim3(8, 98), blk, 0, stream>>>(
        h_b, W1_t, b1, nullptr, nullptr, ff1_b, MQ, FF, HID);
    // pre2 = ff1 @ W2 + b2 + h   grid 4x196
    mgemm64<OP_RES, true, false><<<dim3(4, 196), blk, 0, stream>>>(
        ff1_b, W2_t, b2, ob, q_in_f, nullptr, MQ, HID, FF);
    ln_kernel<<<MQ / 4, blk, 0, stream>>>(q_in_f, g2, be2, h_b);
    // m1 = gelu(h2 @ M1 + bm1)   grid 8x98
    mgemm<OP_GELU, false, true><<<dim3(8, 98), blk, 0, stream>>>(
        h_b, M1_t, bm1, nullptr, nullptr, m1_b, MQ, 2 * HID, HID);
    // out = m1 @ M2 + bm2   grid 7x98
    mgemm<OP_BIAS, true, false><<<dim3(7, 98), blk, 0, stream>>>(
        m1_b, M2_t, bm2, nullptr, out, nullptr, MQ, OUTD, 2 * HID);
}

// Round 8
// 565.789 us; speedup vs baseline: 1.4224x; 1.0073x over previous
//
#include <hip/hip_runtime.h>
#include <cstdint>
#include <cstddef>

// ---------------- dims ----------------
#define BATCH 2
#define MQ 12544          // B * TQ * NQ
#define ROWS_Q 6272
#define MK 4096           // B * T*H*W
#define ROWS_K 2048
#define HID 512
#define NH 4
#define HD 128
#define EMB 1024
#define DQ 896
#define FF 1024
#define OUTD 896

typedef __bf16 bf16;
typedef unsigned int u32;
typedef bf16 bf16x8 __attribute__((ext_vector_type(8)));
typedef bf16 bf16x4 __attribute__((ext_vector_type(4)));
typedef float f32x4 __attribute__((ext_vector_type(4)));

enum { OP_BIAS = 0, OP_GELU = 1, OP_RES = 2 };

__device__ __forceinline__ float gelu_tanh(float x) {
    float x3 = x * x * x;
    return 0.5f * x * (1.0f + tanhf(0.7978845608028654f * (x + 0.044715f * x3)));
}

__device__ __forceinline__ void gld16(const bf16* g, bf16* l) {
    __builtin_amdgcn_global_load_lds(
        (const __attribute__((address_space(1))) unsigned int*)g,
        (__attribute__((address_space(3))) unsigned int*)l, 16, 0, 0);
}

__device__ __forceinline__ u32 pack_bf16(float a, float b) {
    union { bf16 h[2]; u32 w; } u;
    u.h[0] = (bf16)a; u.h[1] = (bf16)b;
    return u.w;
}

// ---------------------------------------------------------------------------
// bf16 MFMA GEMM, 128x128 tile, 2-phase prefetch (T3-minimum, m248v2):
// each BK=32 sub-tile's gld16 loads are issued one full MFMA phase BEFORE the
// barrier that drains them (R7 issued right before the drain -> latency fully
// exposed). Same barrier count as R7's BK=64 (2 per K=64), same LDS (32 KB),
// zero extra registers (gld16 is DMA), same K accumulation order -> bitwise-
// identical results. Requires K % 64 == 0 (all call sites: 512/1024).
// ---------------------------------------------------------------------------
template <int OP, bool WF32, bool WB16>
__global__ __launch_bounds__(256) void mgemm(
    const bf16* __restrict__ A, const bf16* __restrict__ Bt,
    const float* __restrict__ bias, const float* __restrict__ res,
    float* __restrict__ Cf, bf16* __restrict__ Cb, int M, int N, int K)
{
    __shared__ __align__(16) bf16 As0[128 * 32];
    __shared__ __align__(16) bf16 As1[128 * 32];
    __shared__ __align__(16) bf16 Bs0[128 * 32];
    __shared__ __align__(16) bf16 Bs1[128 * 32];
    const int tid  = threadIdx.x;
    const int m0   = blockIdx.y * 128;
    const int n0   = blockIdx.x * 128;
    const int wave = tid >> 6, lane = tid & 63;
    const int wm = (wave >> 1) * 64, wn = (wave & 1) * 64;

    f32x4 acc[4][4] = {};

    const int srow = tid >> 2;
    const int scol = (tid & 3) * 8;
    const bf16* Ag = A  + (size_t)(m0 + srow) * K + scol;
    const bf16* Bg = Bt + (size_t)(n0 + srow) * K + scol;
    bf16* Al0 = &As0[tid * 8];
    bf16* Al1 = &As1[tid * 8];
    bf16* Bl0 = &Bs0[tid * 8];
    bf16* Bl1 = &Bs1[tid * 8];
    const size_t half = (size_t)64 * K;

    const int fr = lane & 15;
    const int kq = (lane >> 4) * 8;
    const bf16* pa0 = &As0[(wm + fr) * 32 + kq];
    const bf16* pa1 = &As1[(wm + fr) * 32 + kq];
    const bf16* pb0 = &Bs0[(wn + fr) * 32 + kq];
    const bf16* pb1 = &Bs1[(wn + fr) * 32 + kq];

    // prologue: sub-tile 0 -> buf0
    gld16(Ag,        Al0);
    gld16(Ag + half, Al0 + 64 * 32);
    gld16(Bg,        Bl0);
    gld16(Bg + half, Bl0 + 64 * 32);

    for (int k0 = 0; k0 < K; k0 += 64) {
        __syncthreads();                       // buf0 (k0) ready
        // prefetch k0+32 -> buf1; flies under computeA
        gld16(Ag + k0 + 32,        Al1);
        gld16(Ag + k0 + 32 + half, Al1 + 64 * 32);
        gld16(Bg + k0 + 32,        Bl1);
        gld16(Bg + k0 + 32 + half, Bl1 + 64 * 32);
        {
            bf16x8 af[4], bfr[4];
            #pragma unroll
            for (int i = 0; i < 4; ++i) af[i]  = *(const bf16x8*)(pa0 + i * 16 * 32);
            #pragma unroll
            for (int j = 0; j < 4; ++j) bfr[j] = *(const bf16x8*)(pb0 + j * 16 * 32);
            #pragma unroll
            for (int i = 0; i < 4; ++i)
                #pragma unroll
                for (int j = 0; j < 4; ++j)
                    acc[i][j] = __builtin_amdgcn_mfma_f32_16x16x32_bf16(
                        af[i], bfr[j], acc[i][j], 0, 0, 0);
        }
        __syncthreads();                       // buf1 (k0+32) ready
        if (k0 + 64 < K) {
            // prefetch k0+64 -> buf0; flies under computeB
            gld16(Ag + k0 + 64,        Al0);
            gld16(Ag + k0 + 64 + half, Al0 + 64 * 32);
            gld16(Bg + k0 + 64,        Bl0);
            gld16(Bg + k0 + 64 + half, Bl0 + 64 * 32);
        }
        {
            bf16x8 af[4], bfr[4];
            #pragma unroll
            for (int i = 0; i < 4; ++i) af[i]  = *(const bf16x8*)(pa1 + i * 16 * 32);
            #pragma unroll
            for (int j = 0; j < 4; ++j) bfr[j] = *(const bf16x8*)(pb1 + j * 16 * 32);
            #pragma unroll
            for (int i = 0; i < 4; ++i)
                #pragma unroll
                for (int j = 0; j < 4; ++j)
                    acc[i][j] = __builtin_amdgcn_mfma_f32_16x16x32_bf16(
                        af[i], bfr[j], acc[i][j], 0, 0, 0);
        }
    }

    const int colb = n0 + wn + (lane & 15);
    const int rowb = m0 + wm + (lane >> 4) * 4;
    #pragma unroll
    for (int i = 0; i < 4; ++i) {
        #pragma unroll
        for (int j = 0; j < 4; ++j) {
            const int c = colb + j * 16;
            const float bj = bias[c];
            #pragma unroll
            for (int r = 0; r < 4; ++r) {
                const int m = rowb + i * 16 + r;
                float v = acc[i][j][r] + bj;
                if (OP == OP_GELU) v = gelu_tanh(v);
                if (OP == OP_RES)  v += res[(size_t)m * N + c];
                if (WF32) Cf[(size_t)m * N + c] = v;
                if (WB16) Cb[(size_t)m * N + c] = (bf16)v;
            }
        }
    }
}

// ---------------------------------------------------------------------------
// bf16 MFMA GEMM, 64x128 tile, 2-phase prefetch (same rationale as mgemm).
// LDS 24 KB. Requires K % 64 == 0 (call sites: 896/512/1024).
// ---------------------------------------------------------------------------
template <int OP, bool WF32, bool WB16>
__global__ __launch_bounds__(256) void mgemm64(
    const bf16* __restrict__ A, const bf16* __restrict__ Bt,
    const float* __restrict__ bias, const float* __restrict__ res,
    float* __restrict__ Cf, bf16* __restrict__ Cb, int M, int N, int K)
{
    __shared__ __align__(16) bf16 As0[64 * 32];
    __shared__ __align__(16) bf16 As1[64 * 32];
    __shared__ __align__(16) bf16 Bs0[128 * 32];
    __shared__ __align__(16) bf16 Bs1[128 * 32];
    const int tid  = threadIdx.x;
    const int m0   = blockIdx.y * 64;
    const int n0   = blockIdx.x * 128;
    const int wave = tid >> 6, lane = tid & 63;
    const int wm = (wave >> 1) * 32, wn = (wave & 1) * 64;

    f32x4 acc[2][4] = {};

    const int srow = tid >> 2;
    const int scol = (tid & 3) * 8;
    const bf16* Ag = A  + (size_t)(m0 + srow) * K + scol;
    const bf16* Bg = Bt + (size_t)(n0 + srow) * K + scol;
    bf16* Al0 = &As0[tid * 8];
    bf16* Al1 = &As1[tid * 8];
    bf16* Bl0 = &Bs0[tid * 8];
    bf16* Bl1 = &Bs1[tid * 8];
    const size_t half = (size_t)64 * K;

    const int fr = lane & 15;
    const int kq = (lane >> 4) * 8;
    const bf16* pa0 = &As0[(wm + fr) * 32 + kq];
    const bf16* pa1 = &As1[(wm + fr) * 32 + kq];
    const bf16* pb0 = &Bs0[(wn + fr) * 32 + kq];
    const bf16* pb1 = &Bs1[(wn + fr) * 32 + kq];

    // prologue: sub-tile 0 -> buf0
    gld16(Ag,        Al0);
    gld16(Bg,        Bl0);
    gld16(Bg + half, Bl0 + 64 * 32);

    for (int k0 = 0; k0 < K; k0 += 64) {
        __syncthreads();                       // buf0 (k0) ready
        gld16(Ag + k0 + 32,        Al1);
        gld16(Bg + k0 + 32,        Bl1);
        gld16(Bg + k0 + 32 + half, Bl1 + 64 * 32);
        {
            bf16x8 af[2], bfr[4];
            #pragma unroll
            for (int i = 0; i < 2; ++i) af[i]  = *(const bf16x8*)(pa0 + i * 16 * 32);
            #pragma unroll
            for (int j = 0; j < 4; ++j) bfr[j] = *(const bf16x8*)(pb0 + j * 16 * 32);
            #pragma unroll
            for (int i = 0; i < 2; ++i)
                #pragma unroll
                for (int j = 0; j < 4; ++j)
                    acc[i][j] = __builtin_amdgcn_mfma_f32_16x16x32_bf16(
                        af[i], bfr[j], acc[i][j], 0, 0, 0);
        }
        __syncthreads();                       // buf1 (k0+32) ready
        if (k0 + 64 < K) {
            gld16(Ag + k0 + 64,        Al0);
            gld16(Bg + k0 + 64,        Bl0);
            gld16(Bg + k0 + 64 + half, Bl0 + 64 * 32);
        }
        {
            bf16x8 af[2], bfr[4];
            #pragma unroll
            for (int i = 0; i < 2; ++i) af[i]  = *(const bf16x8*)(pa1 + i * 16 * 32);
            #pragma unroll
            for (int j = 0; j < 4; ++j) bfr[j] = *(const bf16x8*)(pb1 + j * 16 * 32);
            #pragma unroll
            for (int i = 0; i < 2; ++i)
                #pragma unroll
                for (int j = 0; j < 4; ++j)
                    acc[i][j] = __builtin_amdgcn_mfma_f32_16x16x32_bf16(
                        af[i], bfr[j], acc[i][j], 0, 0, 0);
        }
    }

    const int colb = n0 + wn + (lane & 15);
    const int rowb = m0 + wm + (lane >> 4) * 4;
    #pragma unroll
    for (int i = 0; i < 2; ++i) {
        #pragma unroll
        for (int j = 0; j < 4; ++j) {
            const int c = colb + j * 16;
            const float bj = bias[c];
            #pragma unroll
            for (int r = 0; r < 4; ++r) {
                const int m = rowb + i * 16 + r;
                float v = acc[i][j][r] + bj;
                if (OP == OP_GELU) v = gelu_tanh(v);
                if (OP == OP_RES)  v += res[(size_t)m * N + c];
                if (WF32) Cf[(size_t)m * N + c] = v;
                if (WB16) Cb[(size_t)m * N + c] = (bf16)v;
            }
        }
    }
}

// ---------------------------------------------------------------------------
// All 9 weight transposes (fp32 KxN -> bf16 NxK) in ONE launch.
// ---------------------------------------------------------------------------
struct TDesc { const float* src; bf16* dst; int K; int N; int tile0; };
struct TDescs { TDesc d[9]; };

__global__ __launch_bounds__(256) void transpose_all(TDescs td)
{
    __shared__ float t[32][33];
    const int blk = blockIdx.x;
    int i = 0;
    #pragma unroll
    for (int j = 1; j < 9; ++j) if (blk >= td.d[j].tile0) i = j;
    const float* src = td.d[i].src;
    bf16* dst = td.d[i].dst;
    const int K = td.d[i].K, N = td.d[i].N;
    const int local = blk - td.d[i].tile0;
    const int ntx = N >> 5;
    const int bx = local % ntx, by = local / ntx;
    const int x = threadIdx.x & 31, y = threadIdx.x >> 5;
    #pragma unroll
    for (int p = 0; p < 32; p += 8)
        t[y + p][x] = src[(size_t)(by * 32 + y + p) * N + bx * 32 + x];
    __syncthreads();
    #pragma unroll
    for (int p = 0; p < 32; p += 8)
        dst[(size_t)(bx * 32 + y + p) * K + by * 32 + x] = (bf16)t[x][y + p];
}

// fp32 -> bf16 elementwise
__global__ __launch_bounds__(256) void cvt_kernel(
    const float* __restrict__ in, bf16* __restrict__ out, int n4)
{
    int i = blockIdx.x * 256 + threadIdx.x;
    if (i >= n4) return;
    float4 v = ((const float4*)in)[i];
    out[4 * i + 0] = (bf16)v.x;
    out[4 * i + 1] = (bf16)v.y;
    out[4 * i + 2] = (bf16)v.z;
    out[4 * i + 3] = (bf16)v.w;
}

// kv = x @ Wm + bm  (K=4), bf16 out.
__global__ __launch_bounds__(256) void kv_kernel(
    const float* __restrict__ x, const float* __restrict__ Wm,
    const float* __restrict__ bm, bf16* __restrict__ kv)
{
    int idx = blockIdx.x * 256 + threadIdx.x;
    int r = idx >> 10, n = idx & 1023;
    float4 xv = *(const float4*)(x + (size_t)r * 4);
    float v = bm[n] + xv.x * Wm[n] + xv.y * Wm[1024 + n]
                    + xv.z * Wm[2048 + n] + xv.w * Wm[3072 + n];
    kv[idx] = (bf16)v;
}

// RoPE cos/sin table: tab[f*32+pos] = (cos, sin)(pos * 2^(-f*c)), f in [0,64),
// pos in [0,32). Same float expressions as the old in-kernel computation ->
// bitwise-identical values, computed 2048x instead of ~2.1M x.
__global__ __launch_bounds__(256) void rope_tab_kernel(float2* __restrict__ tab)
{
    int i = blockIdx.x * 256 + threadIdx.x;
    if (i >= 64 * 32) return;
    int f = i >> 5, pos = i & 31;
    float ang = (float)pos * exp2f(-(float)f * 0.20762050593045954f);
    tab[i] = make_float2(cosf(ang), sinf(ang));
}

// 3D RoPE: bf16 in (row stride istr, col offset icoff) -> bf16 out (rows x 512).
// Trig replaced by table lookups (bitwise-identical values).
__global__ __launch_bounds__(256) void rope_b_kernel(
    const bf16* __restrict__ in, bf16* __restrict__ out,
    const float2* __restrict__ tab,
    int tok, int gdiv, int wdiv, int total, float sc, int istr, int icoff)
{
    int idx = blockIdx.x * 256 + threadIdx.x;
    if (idx >= total) return;
    int row = idx >> 7;
    int r2 = idx & 127;
    int h = r2 >> 5;
    int j2 = r2 & 31;
    int j = 2 * j2;
    int n = row % tok;
    int t = n / gdiv;
    int g = n % gdiv;
    int gh = g / wdiv;
    int gw = g % wdiv;
    int j1 = j + 1;
    int pa_i = (j < 22)  ? t : (j < 43)  ? gh : gw;
    int pb_i = (j1 < 22) ? t : (j1 < 43) ? gh : gw;
    float2 ta = tab[j * 32 + pa_i];
    float2 tb = tab[j1 * 32 + pb_i];
    float ca = ta.x, sa = ta.y;
    float cb = tb.x, sb = tb.y;
    size_t ibase = (size_t)row * istr + icoff + (size_t)h * 128 + j;
    size_t obase = (size_t)row * 512 + (size_t)h * 128 + j;
    union { u32 w; bf16 e[2]; } ua, ub;
    ua.w = *(const u32*)(in + ibase);
    ub.w = *(const u32*)(in + ibase + 64);
    float x1a = (float)ua.e[0], x1b = (float)ua.e[1];
    float x2a = (float)ub.e[0], x2b = (float)ub.e[1];
    *(u32*)(out + obase)      = pack_bf16((x1a * ca - x2a * sa) * sc,
                                          (x1b * cb - x2b * sb) * sc);
    *(u32*)(out + obase + 64) = pack_bf16((x2a * ca + x1a * sa) * sc,
                                          (x2b * cb + x1b * sb) * sc);
}

// Coalesced V transpose: kv16[t][512 + h*128 + d] -> Vt[b][h][d][2048]
__global__ __launch_bounds__(256) void vt_tiled(
    const bf16* __restrict__ kv16, bf16* __restrict__ vt)
{
    __shared__ bf16 t[64][72];
    const int tt = blockIdx.x * 64;
    const int d0 = blockIdx.y * 64;
    const int bh = blockIdx.z;
    const int b = bh >> 2, h = bh & 3;
    const int rr = threadIdx.x >> 4;
    const int cc = (threadIdx.x & 15) * 4;
    #pragma unroll
    for (int p = 0; p < 4; ++p) {
        int r = rr + p * 16;
        *(bf16x4*)&t[r][cc] = *(const bf16x4*)
            (kv16 + (size_t)(b * ROWS_K + tt + r) * 1024 + 512 + h * 128 + d0 + cc);
    }
    __syncthreads();
    #pragma unroll
    for (int p = 0; p < 4; ++p) {
        int r = rr + p * 16;   // d-local
        bf16x4 v;
        v[0] = t[cc + 0][r]; v[1] = t[cc + 1][r];
        v[2] = t[cc + 2][r]; v[3] = t[cc + 3][r];
        *(bf16x4*)(vt + (size_t)bh * HD * ROWS_K + (size_t)(d0 + r) * ROWS_K + tt + cc) = v;
    }
}

// LayerNorm in-place on (rows x 512) + bf16 copy.
__global__ __launch_bounds__(256) void ln_kernel(
    float* __restrict__ xb, const float* __restrict__ g,
    const float* __restrict__ be, bf16* __restrict__ out16)
{
    int wave = threadIdx.x >> 6, lane = threadIdx.x & 63;
    size_t row = (size_t)blockIdx.x * 4 + wave;
    float* xp = xb + row * 512;
    float4 a = ((const float4*)xp)[lane];
    float4 b = ((const float4*)xp)[lane + 64];
    float s  = a.x + a.y + a.z + a.w + b.x + b.y + b.z + b.w;
    float sq = a.x*a.x + a.y*a.y + a.z*a.z + a.w*a.w
             + b.x*b.x + b.y*b.y + b.z*b.z + b.w*b.w;
    #pragma unroll
    for (int off = 32; off; off >>= 1) {
        s  += __shfl_xor(s, off);
        sq += __shfl_xor(sq, off);
    }
    float mean = s * (1.0f / 512.0f);
    float var  = sq * (1.0f / 512.0f) - mean * mean;
    float rstd = rsqrtf(var + 1e-5f);
    float4 gv1 = ((const float4*)g)[lane],  gv2 = ((const float4*)g)[lane + 64];
    float4 bv1 = ((const float4*)be)[lane], bv2 = ((const float4*)be)[lane + 64];
    a.x = (a.x - mean) * rstd * gv1.x + bv1.x;
    a.y = (a.y - mean) * rstd * gv1.y + bv1.y;
    a.z = (a.z - mean) * rstd * gv1.z + bv1.z;
    a.w = (a.w - mean) * rstd * gv1.w + bv1.w;
    b.x = (b.x - mean) * rstd * gv2.x + bv2.x;
    b.y = (b.y - mean) * rstd * gv2.y + bv2.y;
    b.z = (b.z - mean) * rstd * gv2.z + bv2.z;
    b.w = (b.w - mean) * rstd * gv2.w + bv2.w;
    ((float4*)xp)[lane]      = a;
    ((float4*)xp)[lane + 64] = b;
    bf16* op = out16 + row * 512;
    *(u32*)(op + lane * 4)       = pack_bf16(a.x, a.y);
    *(u32*)(op + lane * 4 + 2)   = pack_bf16(a.z, a.w);
    *(u32*)(op + 256 + lane * 4)     = pack_bf16(b.x, b.y);
    *(u32*)(op + 256 + lane * 4 + 2) = pack_bf16(b.z, b.w);
}

// ---------------------------------------------------------------------------
// MFMA flash attention — FROZEN at the R7 configuration (verbatim round-0
// body, strides 136/72/136, XCD swizzle). R6/R7 established: structure-bound
// at ~121us (1 block/CU residency from the unified VGPR+acc budget); grid,
// split, and traffic changes are neutral; per-wave restructures break
// regalloc (rounds 1-4); padded strides were a 3x LDS-misalignment trap (R5).
// ---------------------------------------------------------------------------
__global__ __launch_bounds__(256, 2) void mattn_kernel(
    const bf16* __restrict__ qs, const bf16* __restrict__ ks,
    const bf16* __restrict__ vt, bf16* __restrict__ outb)
{
    __shared__ __align__(16) char smem[35840];
    bf16* Ksh = (bf16*)smem;            // [64][136]
    bf16* Vsh = (bf16*)(smem + 17408);  // [128][72]

    const int tid = threadIdx.x;
    const int wave = tid >> 6, lane = tid & 63;
    const int quad = lane >> 4, c = lane & 15;
    const int bid = blockIdx.x;
    const int bh = bid & 7;             // XCD-locality: same (b,h) -> same XCD
    const int qt = bid >> 3;
    const int h  = bh & 3;
    const int b  = bh >> 2;

    const int q0 = qt * 128 + wave * 32;
    const bf16* qg = qs + (size_t)(b * ROWS_Q + q0) * HID + h * HD;
    const bf16* kg = ks + (size_t)(b * ROWS_K) * HID + h * HD;
    const bf16* vg = vt + (size_t)(b * NH + h) * HD * ROWS_K;

    bf16x8 qf[2][4];
    #pragma unroll
    for (int n = 0; n < 2; ++n)
        #pragma unroll
        for (int s = 0; s < 4; ++s)
            qf[n][s] = *(const bf16x8*)(qg + (size_t)(n * 16 + c) * HID + s * 32 + quad * 8);

    f32x4 o[8][2] = {};
    float m_i[2] = {-1e30f, -1e30f}, l_i[2] = {0.0f, 0.0f};

    const int st_t = tid >> 2;
    const int st_d = (tid & 3) * 32;
    const int sv_d = tid >> 1;
    const int sv_t = (tid & 1) * 32;

    for (int kt = 0; kt < 32; ++kt) {
        __syncthreads();
        {
            const bf16* src = kg + (size_t)(kt * 64 + st_t) * HID + st_d;
            bf16* dst = Ksh + st_t * 136 + st_d;
            #pragma unroll
            for (int i = 0; i < 4; ++i)
                *(bf16x8*)(dst + i * 8) = *(const bf16x8*)(src + i * 8);
        }
        {
            const bf16* src = vg + (size_t)sv_d * ROWS_K + kt * 64 + sv_t;
            bf16* dst = Vsh + sv_d * 72 + sv_t;
            #pragma unroll
            for (int i = 0; i < 4; ++i)
                *(bf16x8*)(dst + i * 8) = *(const bf16x8*)(src + i * 8);
        }
        __syncthreads();

        f32x4 s[4][2] = {};
        #pragma unroll
        for (int ksi = 0; ksi < 4; ++ksi) {
            bf16x8 kf[4];
            #pragma unroll
            for (int mi = 0; mi < 4; ++mi)
                kf[mi] = *(const bf16x8*)(Ksh + (mi * 16 + c) * 136 + ksi * 32 + quad * 8);
            #pragma unroll
            for (int mi = 0; mi < 4; ++mi)
                #pragma unroll
                for (int n = 0; n < 2; ++n)
                    s[mi][n] = __builtin_amdgcn_mfma_f32_16x16x32_bf16(
                        kf[mi], qf[n][ksi], s[mi][n], 0, 0, 0);
        }

        float alpha[2];
        #pragma unroll
        for (int n = 0; n < 2; ++n) {
            float mx = -1e30f;
            #pragma unroll
            for (int mi = 0; mi < 4; ++mi)
                #pragma unroll
                for (int r = 0; r < 4; ++r) mx = fmaxf(mx, s[mi][n][r]);
            mx = fmaxf(mx, __shfl_xor(mx, 16));
            mx = fmaxf(mx, __shfl_xor(mx, 32));
            float mn = fmaxf(m_i[n], mx);
            alpha[n] = __expf(m_i[n] - mn);
            m_i[n] = mn;
            float sm = 0.0f;
            #pragma unroll
            for (int mi = 0; mi < 4; ++mi)
                #pragma unroll
                for (int r = 0; r < 4; ++r) {
                    float p = __expf(s[mi][n][r] - mn);
                    s[mi][n][r] = p;
                    sm += p;
                }
            sm += __shfl_xor(sm, 16);
            sm += __shfl_xor(sm, 32);
            l_i[n] = l_i[n] * alpha[n] + sm;
            #pragma unroll
            for (int md = 0; md < 8; ++md) {
                o[md][n][0] *= alpha[n]; o[md][n][1] *= alpha[n];
                o[md][n][2] *= alpha[n]; o[md][n][3] *= alpha[n];
            }
        }

        u32 pk[4][2][2];
        #pragma unroll
        for (int mi = 0; mi < 4; ++mi)
            #pragma unroll
            for (int n = 0; n < 2; ++n) {
                pk[mi][n][0] = pack_bf16(s[mi][n][0], s[mi][n][1]);
                pk[mi][n][1] = pack_bf16(s[mi][n][2], s[mi][n][3]);
            }
        bf16x8 pf[2][2];
        #pragma unroll
        for (int kst = 0; kst < 2; ++kst)
            #pragma unroll
            for (int n = 0; n < 2; ++n) {
                union { bf16x8 v8; u32 d[4]; } u;
                #pragma unroll
                for (int dw = 0; dw < 4; ++dw) {
                    int srcl = ((quad & 1) * 2 + (dw >> 1)) * 16 + c;
                    u32 lo = (u32)__shfl((int)pk[2 * kst][n][dw & 1], srcl);
                    u32 hi = (u32)__shfl((int)pk[2 * kst + 1][n][dw & 1], srcl);
                    u.d[dw] = (quad >= 2) ? hi : lo;
                }
                pf[kst][n] = u.v8;
            }

        #pragma unroll
        for (int kst = 0; kst < 2; ++kst)
            #pragma unroll
            for (int md = 0; md < 8; ++md) {
                bf16x8 vf = *(const bf16x8*)(Vsh + (md * 16 + c) * 72 + kst * 32 + quad * 8);
                #pragma unroll
                for (int n = 0; n < 2; ++n)
                    o[md][n] = __builtin_amdgcn_mfma_f32_16x16x32_bf16(
                        vf, pf[kst][n], o[md][n], 0, 0, 0);
            }
    }

    __syncthreads();
    bf16* Osh = (bf16*)smem + wave * (32 * 136);
    float inv[2] = {1.0f / l_i[0], 1.0f / l_i[1]};
    #pragma unroll
    for (int md = 0; md < 8; ++md)
        #pragma unroll
        for (int n = 0; n < 2; ++n)
            #pragma unroll
            for (int hh = 0; hh < 2; ++hh) {
                u32 w = pack_bf16(o[md][n][2 * hh] * inv[n], o[md][n][2 * hh + 1] * inv[n]);
                int d = md * 16 + quad * 4 + 2 * hh;
                int qq = n * 16 + c;
                *(u32*)(Osh + qq * 136 + d) = w;
            }
    __syncthreads();
    bf16* og = outb + (size_t)(b * ROWS_Q + q0) * HID + h * HD;
    #pragma unroll
    for (int i = 0; i < 8; ++i) {
        int idx = i * 64 + lane;
        int qq = idx >> 4;
        int ch = idx & 15;
        bf16x8 vv = *(const bf16x8*)(Osh + qq * 136 + ch * 8);
        *(bf16x8*)(og + (size_t)qq * HID + ch * 8) = vv;
    }
}

extern "C" void kernel_launch(void* const* d_in, const int* in_sizes, int n_in,
                              void* d_out, int out_size, void* d_ws, size_t ws_size,
                              hipStream_t stream)
{
    const float* x     = (const float*)d_in[0];
    const float* slow  = (const float*)d_in[1];
    const float* Wq_in = (const float*)d_in[3];
    const float* bq_in = (const float*)d_in[4];
    const float* Wm    = (const float*)d_in[5];
    const float* bm    = (const float*)d_in[6];
    const float* Wq    = (const float*)d_in[7];
    const float* bq    = (const float*)d_in[8];
    const float* Wk    = (const float*)d_in[9];
    const float* bk    = (const float*)d_in[10];
    const float* Wv    = (const float*)d_in[11];
    const float* bv    = (const float*)d_in[12];
    const float* Wo    = (const float*)d_in[13];
    const float* bo    = (const float*)d_in[14];
    const float* g1    = (const float*)d_in[15];
    const float* be1   = (const float*)d_in[16];
    const float* W1    = (const float*)d_in[17];
    const float* b1    = (const float*)d_in[18];
    const float* W2    = (const float*)d_in[19];
    const float* b2    = (const float*)d_in[20];
    const float* g2    = (const float*)d_in[21];
    const float* be2   = (const float*)d_in[22];
    const float* M1    = (const float*)d_in[23];
    const float* bm1   = (const float*)d_in[24];
    const float* M2    = (const float*)d_in[25];
    const float* bm2   = (const float*)d_in[26];
    float* out = (float*)d_out;

    // ---- workspace layout ----
    float* q_in_f = (float*)d_ws;                         // MQ*512 f32
    float* ob     = q_in_f + (size_t)MQ * HID;            // MQ*512 f32
    float* bkv    = ob + (size_t)MQ * HID;                // 1024 f32
    bf16* shared_b = (bf16*)(bkv + 1024);                 // MQ*1024 (slow_b/attn_b/ff1_b/m1_b)
    bf16* q_in_b = shared_b + (size_t)MQ * FF;            // MQ*512
    bf16* kv_b   = q_in_b + (size_t)MQ * HID;             // MK*1024
    bf16* h_b    = kv_b + (size_t)MK * EMB;               // MQ*512
    bf16* q16    = h_b + (size_t)MQ * HID;                // MQ*512
    bf16* kv16   = q16 + (size_t)MQ * HID;                // MK*1024 (k|v fused)
    bf16* qbt    = kv16 + (size_t)MK * EMB;               // MQ*512
    bf16* kbt    = qbt + (size_t)MQ * HID;                // MK*512
    bf16* Vt     = kbt + (size_t)MK * HID;                // 8*128*2048
    bf16* Wq_in_t = Vt + (size_t)8 * HD * ROWS_K;         // 512*896
    bf16* Wq_t  = Wq_in_t + 512 * 896;                    // 512*512
    bf16* kvw_t = Wq_t + 512 * 512;                       // 1024*1024 (Wk_t | Wv_t)
    bf16* Wo_t  = kvw_t + 1024 * 1024;                    // 512*512
    bf16* W1_t  = Wo_t + 512 * 512;                       // 1024*512
    bf16* W2_t  = W1_t + 1024 * 512;                      // 512*1024
    bf16* M1_t  = W2_t + 512 * 1024;                      // 1024*512
    bf16* M2_t  = M1_t + 1024 * 512;                      // 896*1024
    bf16* slow_b = shared_b;
    bf16* attn_b = shared_b;
    bf16* ff1_b  = shared_b;
    bf16* m1_b   = shared_b;

    // RoPE cos/sin table: lives in ob (dead until the Wo GEMM, long after rope)
    float2* rtab = (float2*)ob;                           // 64*32 float2 = 16 KB

    dim3 blk(256);

    // ---- all weight transposes in one launch ----
    TDescs td;
    int t0 = 0;
    auto set = [&](int i, const float* s, bf16* d, int K, int N) {
        td.d[i] = {s, d, K, N, t0};
        t0 += (N / 32) * (K / 32);
    };
    set(0, Wq_in, Wq_in_t, 896, 512);
    set(1, Wq,    Wq_t,    512, 512);
    set(2, Wk,    kvw_t,              1024, 512);
    set(3, Wv,    kvw_t + 512 * 1024, 1024, 512);
    set(4, Wo,    Wo_t,    512, 512);
    set(5, W1,    W1_t,    512, 1024);
    set(6, W2,    W2_t,    1024, 512);
    set(7, M1,    M1_t,    512, 1024);
    set(8, M2,    M2_t,    1024, 896);
    transpose_all<<<t0, blk, 0, stream>>>(td);

    // bias concat for fused KV GEMM
    hipMemcpyAsync(bkv,       bk, 512 * sizeof(float), hipMemcpyDeviceToDevice, stream);
    hipMemcpyAsync(bkv + 512, bv, 512 * sizeof(float), hipMemcpyDeviceToDevice, stream);

    rope_tab_kernel<<<8, blk, 0, stream>>>(rtab);
    cvt_kernel<<<(MQ * DQ / 4 + 255) / 256, blk, 0, stream>>>(slow, slow_b, MQ * DQ / 4);
    kv_kernel<<<(MK * EMB) / 256, blk, 0, stream>>>(x, Wm, bm, kv_b);

    // q_in = slow @ Wq_in + bq_in -> fp32 (residual) + bf16   grid 4x196
    mgemm64<OP_BIAS, true, true><<<dim3(4, 196), blk, 0, stream>>>(
        slow_b, Wq_in_t, bq_in, nullptr, q_in_f, q_in_b, MQ, HID, DQ);
    // q projection -> bf16   grid 4x196
    mgemm64<OP_BIAS, false, true><<<dim3(4, 196), blk, 0, stream>>>(
        q_in_b, Wq_t, bq, nullptr, nullptr, q16, MQ, HID, HID);
    // fused k|v projection -> kv16 (MK x 1024)   grid 8x64
    mgemm64<OP_BIAS, false, true><<<dim3(8, 64), blk, 0, stream>>>(
        kv_b, kvw_t, bkv, nullptr, nullptr, kv16, MK, 1024, EMB);
    // RoPE (q pre-scaled by 1/sqrt(128)); k read from fused kv16
    rope_b_kernel<<<(MQ * 128 + 255) / 256, blk, 0, stream>>>(
        q16, qbt, rtab, ROWS_Q, 196, 14, MQ * 128, 0.08838834764831843f, 512, 0);
    rope_b_kernel<<<(MK * 128 + 255) / 256, blk, 0, stream>>>(
        kv16, kbt, rtab, ROWS_K, 64, 8, MK * 128, 1.0f, 1024, 0);
    // V transpose (coalesced)
    vt_tiled<<<dim3(32, 2, 8), blk, 0, stream>>>(kv16, Vt);
    // MFMA flash attention -> attn_b (bf16), grid 392, XCD-swizzled
    mattn_kernel<<<dim3(392), blk, 0, stream>>>(qbt, kbt, Vt, attn_b);
    // pre_ln = attn @ Wo + bo + q_in   grid 4x196
    mgemm64<OP_RES, true, false><<<dim3(4, 196), blk, 0, stream>>>(
        attn_b, Wo_t, bo, q_in_f, ob, nullptr, MQ, HID, HID);
    ln_kernel<<<MQ / 4, blk, 0, stream>>>(ob, g1, be1, h_b);
    // ff1 = gelu(h @ W1 + b1)   grid 8x98 (128-tile)
    mgemm<OP_GELU, false, true><<<dim3(8, 98), blk, 0, stream>>>(
        h_b, W1_t, b1, nullptr, nullptr, ff1_b, MQ, FF, HID);
    // pre2 = ff1 @ W2 + b2 + h   grid 4x196
    mgemm64<OP_RES, true, false><<<dim3(4, 196), blk, 0, stream>>>(
        ff1_b, W2_t, b2, ob, q_in_f, nullptr, MQ, HID, FF);
    ln_kernel<<<MQ / 4, blk, 0, stream>>>(q_in_f, g2, be2, h_b);
    // m1 = gelu(h2 @ M1 + bm1)   grid 8x98
    mgemm<OP_GELU, false, true><<<dim3(8, 98), blk, 0, stream>>>(
        h_b, M1_t, bm1, nullptr, nullptr, m1_b, MQ, 2 * HID, HID);
    // out = m1 @ M2 + bm2   grid 7x98
    mgemm<OP_BIAS, true, false><<<dim3(7, 98), blk, 0, stream>>>(
        m1_b, M2_t, bm2, nullptr, out, nullptr, MQ, OUTD, 2 * HID);
}

// Round 9
// 553.188 us; speedup vs baseline: 1.4548x; 1.0228x over previous
//
#include <hip/hip_runtime.h>
#include <cstdint>
#include <cstddef>

// ---------------- dims ----------------
#define BATCH 2
#define MQ 12544          // B * TQ * NQ
#define ROWS_Q 6272
#define MK 4096           // B * T*H*W
#define ROWS_K 2048
#define HID 512
#define NH 4
#define HD 128
#define EMB 1024
#define DQ 896
#define FF 1024
#define OUTD 896

typedef __bf16 bf16;
typedef unsigned int u32;
typedef bf16 bf16x8 __attribute__((ext_vector_type(8)));
typedef bf16 bf16x4 __attribute__((ext_vector_type(4)));
typedef float f32x4 __attribute__((ext_vector_type(4)));
typedef float f32x16 __attribute__((ext_vector_type(16)));

enum { OP_BIAS = 0, OP_GELU = 1, OP_RES = 2 };

__device__ __forceinline__ float gelu_tanh(float x) {
    float x3 = x * x * x;
    return 0.5f * x * (1.0f + tanhf(0.7978845608028654f * (x + 0.044715f * x3)));
}

__device__ __forceinline__ void gld16(const bf16* g, bf16* l) {
    __builtin_amdgcn_global_load_lds(
        (const __attribute__((address_space(1))) unsigned int*)g,
        (__attribute__((address_space(3))) unsigned int*)l, 16, 0, 0);
}

__device__ __forceinline__ u32 pack_bf16(float a, float b) {
    union { bf16 h[2]; u32 w; } u;
    u.h[0] = (bf16)a; u.h[1] = (bf16)b;
    return u.w;
}

// ---------------------------------------------------------------------------
// bf16 MFMA GEMM, 128x128 tile, 2-phase prefetch, 32x32x16 MFMA.
// Round-9: switched from 16 x mfma_16x16x32 (5cyc/16kF) to 8 x mfma_32x32x16
// (8cyc/32kF) per BK=32 phase: 1.25x FLOP/issue-cycle (ubench 2382 vs 2075
// TF), half the MFMA instruction count + acc-init. Staging, barriers, grid,
// LDS (32 KB) unchanged from R8. Fragment layouts (gfx950):
//   A: row=lane&31, k=(lane>>5)*8+j;  B: col=lane&31, same k
//   C/D: col=lane&31, row=(reg&3)+8*(reg>>2)+4*(lane>>5)   [m74/m101]
// ---------------------------------------------------------------------------
template <int OP, bool WF32, bool WB16>
__global__ __launch_bounds__(256) void mgemm(
    const bf16* __restrict__ A, const bf16* __restrict__ Bt,
    const float* __restrict__ bias, const float* __restrict__ res,
    float* __restrict__ Cf, bf16* __restrict__ Cb, int M, int N, int K)
{
    __shared__ __align__(16) bf16 As0[128 * 32];
    __shared__ __align__(16) bf16 As1[128 * 32];
    __shared__ __align__(16) bf16 Bs0[128 * 32];
    __shared__ __align__(16) bf16 Bs1[128 * 32];
    const int tid  = threadIdx.x;
    const int m0   = blockIdx.y * 128;
    const int n0   = blockIdx.x * 128;
    const int wave = tid >> 6, lane = tid & 63;
    const int wm = (wave >> 1) * 64, wn = (wave & 1) * 64;

    f32x16 acc[2][2] = {};

    const int srow = tid >> 2;
    const int scol = (tid & 3) * 8;
    const bf16* Ag = A  + (size_t)(m0 + srow) * K + scol;
    const bf16* Bg = Bt + (size_t)(n0 + srow) * K + scol;
    bf16* Al0 = &As0[tid * 8];
    bf16* Al1 = &As1[tid * 8];
    bf16* Bl0 = &Bs0[tid * 8];
    bf16* Bl1 = &Bs1[tid * 8];
    const size_t half = (size_t)64 * K;

    const int r32 = lane & 31;
    const int kh  = (lane >> 5) * 8;
    const bf16* pa0 = &As0[(wm + r32) * 32 + kh];
    const bf16* pa1 = &As1[(wm + r32) * 32 + kh];
    const bf16* pb0 = &Bs0[(wn + r32) * 32 + kh];
    const bf16* pb1 = &Bs1[(wn + r32) * 32 + kh];

    // prologue: sub-tile 0 -> buf0
    gld16(Ag,        Al0);
    gld16(Ag + half, Al0 + 64 * 32);
    gld16(Bg,        Bl0);
    gld16(Bg + half, Bl0 + 64 * 32);

    for (int k0 = 0; k0 < K; k0 += 64) {
        __syncthreads();                       // buf0 (k0) ready
        gld16(Ag + k0 + 32,        Al1);
        gld16(Ag + k0 + 32 + half, Al1 + 64 * 32);
        gld16(Bg + k0 + 32,        Bl1);
        gld16(Bg + k0 + 32 + half, Bl1 + 64 * 32);
        {
            bf16x8 af[2][2], bfr[2][2];
            #pragma unroll
            for (int ti = 0; ti < 2; ++ti)
                #pragma unroll
                for (int ks = 0; ks < 2; ++ks) {
                    af[ti][ks]  = *(const bf16x8*)(pa0 + ti * 32 * 32 + ks * 16);
                    bfr[ti][ks] = *(const bf16x8*)(pb0 + ti * 32 * 32 + ks * 16);
                }
            #pragma unroll
            for (int ks = 0; ks < 2; ++ks)
                #pragma unroll
                for (int ti = 0; ti < 2; ++ti)
                    #pragma unroll
                    for (int tj = 0; tj < 2; ++tj)
                        acc[ti][tj] = __builtin_amdgcn_mfma_f32_32x32x16_bf16(
                            af[ti][ks], bfr[tj][ks], acc[ti][tj], 0, 0, 0);
        }
        __syncthreads();                       // buf1 (k0+32) ready
        if (k0 + 64 < K) {
            gld16(Ag + k0 + 64,        Al0);
            gld16(Ag + k0 + 64 + half, Al0 + 64 * 32);
            gld16(Bg + k0 + 64,        Bl0);
            gld16(Bg + k0 + 64 + half, Bl0 + 64 * 32);
        }
        {
            bf16x8 af[2][2], bfr[2][2];
            #pragma unroll
            for (int ti = 0; ti < 2; ++ti)
                #pragma unroll
                for (int ks = 0; ks < 2; ++ks) {
                    af[ti][ks]  = *(const bf16x8*)(pa1 + ti * 32 * 32 + ks * 16);
                    bfr[ti][ks] = *(const bf16x8*)(pb1 + ti * 32 * 32 + ks * 16);
                }
            #pragma unroll
            for (int ks = 0; ks < 2; ++ks)
                #pragma unroll
                for (int ti = 0; ti < 2; ++ti)
                    #pragma unroll
                    for (int tj = 0; tj < 2; ++tj)
                        acc[ti][tj] = __builtin_amdgcn_mfma_f32_32x32x16_bf16(
                            af[ti][ks], bfr[tj][ks], acc[ti][tj], 0, 0, 0);
        }
    }

    const int colb = n0 + wn + (lane & 31);
    const int rowb = m0 + wm + (lane >> 5) * 4;
    #pragma unroll
    for (int ti = 0; ti < 2; ++ti) {
        #pragma unroll
        for (int tj = 0; tj < 2; ++tj) {
            const int c = colb + tj * 32;
            const float bj = bias[c];
            #pragma unroll
            for (int r = 0; r < 16; ++r) {
                const int m = rowb + ti * 32 + (r & 3) + (r >> 2) * 8;
                float v = acc[ti][tj][r] + bj;
                if (OP == OP_GELU) v = gelu_tanh(v);
                if (OP == OP_RES)  v += res[(size_t)m * N + c];
                if (WF32) Cf[(size_t)m * N + c] = v;
                if (WB16) Cb[(size_t)m * N + c] = (bf16)v;
            }
        }
    }
}

// ---------------------------------------------------------------------------
// bf16 MFMA GEMM, 64x128 tile, 2-phase prefetch — UNCHANGED from R8.
// ---------------------------------------------------------------------------
template <int OP, bool WF32, bool WB16>
__global__ __launch_bounds__(256) void mgemm64(
    const bf16* __restrict__ A, const bf16* __restrict__ Bt,
    const float* __restrict__ bias, const float* __restrict__ res,
    float* __restrict__ Cf, bf16* __restrict__ Cb, int M, int N, int K)
{
    __shared__ __align__(16) bf16 As0[64 * 32];
    __shared__ __align__(16) bf16 As1[64 * 32];
    __shared__ __align__(16) bf16 Bs0[128 * 32];
    __shared__ __align__(16) bf16 Bs1[128 * 32];
    const int tid  = threadIdx.x;
    const int m0   = blockIdx.y * 64;
    const int n0   = blockIdx.x * 128;
    const int wave = tid >> 6, lane = tid & 63;
    const int wm = (wave >> 1) * 32, wn = (wave & 1) * 64;

    f32x4 acc[2][4] = {};

    const int srow = tid >> 2;
    const int scol = (tid & 3) * 8;
    const bf16* Ag = A  + (size_t)(m0 + srow) * K + scol;
    const bf16* Bg = Bt + (size_t)(n0 + srow) * K + scol;
    bf16* Al0 = &As0[tid * 8];
    bf16* Al1 = &As1[tid * 8];
    bf16* Bl0 = &Bs0[tid * 8];
    bf16* Bl1 = &Bs1[tid * 8];
    const size_t half = (size_t)64 * K;

    const int fr = lane & 15;
    const int kq = (lane >> 4) * 8;
    const bf16* pa0 = &As0[(wm + fr) * 32 + kq];
    const bf16* pa1 = &As1[(wm + fr) * 32 + kq];
    const bf16* pb0 = &Bs0[(wn + fr) * 32 + kq];
    const bf16* pb1 = &Bs1[(wn + fr) * 32 + kq];

    // prologue: sub-tile 0 -> buf0
    gld16(Ag,        Al0);
    gld16(Bg,        Bl0);
    gld16(Bg + half, Bl0 + 64 * 32);

    for (int k0 = 0; k0 < K; k0 += 64) {
        __syncthreads();                       // buf0 (k0) ready
        gld16(Ag + k0 + 32,        Al1);
        gld16(Bg + k0 + 32,        Bl1);
        gld16(Bg + k0 + 32 + half, Bl1 + 64 * 32);
        {
            bf16x8 af[2], bfr[4];
            #pragma unroll
            for (int i = 0; i < 2; ++i) af[i]  = *(const bf16x8*)(pa0 + i * 16 * 32);
            #pragma unroll
            for (int j = 0; j < 4; ++j) bfr[j] = *(const bf16x8*)(pb0 + j * 16 * 32);
            #pragma unroll
            for (int i = 0; i < 2; ++i)
                #pragma unroll
                for (int j = 0; j < 4; ++j)
                    acc[i][j] = __builtin_amdgcn_mfma_f32_16x16x32_bf16(
                        af[i], bfr[j], acc[i][j], 0, 0, 0);
        }
        __syncthreads();                       // buf1 (k0+32) ready
        if (k0 + 64 < K) {
            gld16(Ag + k0 + 64,        Al0);
            gld16(Bg + k0 + 64,        Bl0);
            gld16(Bg + k0 + 64 + half, Bl0 + 64 * 32);
        }
        {
            bf16x8 af[2], bfr[4];
            #pragma unroll
            for (int i = 0; i < 2; ++i) af[i]  = *(const bf16x8*)(pa1 + i * 16 * 32);
            #pragma unroll
            for (int j = 0; j < 4; ++j) bfr[j] = *(const bf16x8*)(pb1 + j * 16 * 32);
            #pragma unroll
            for (int i = 0; i < 2; ++i)
                #pragma unroll
                for (int j = 0; j < 4; ++j)
                    acc[i][j] = __builtin_amdgcn_mfma_f32_16x16x32_bf16(
                        af[i], bfr[j], acc[i][j], 0, 0, 0);
        }
    }

    const int colb = n0 + wn + (lane & 15);
    const int rowb = m0 + wm + (lane >> 4) * 4;
    #pragma unroll
    for (int i = 0; i < 2; ++i) {
        #pragma unroll
        for (int j = 0; j < 4; ++j) {
            const int c = colb + j * 16;
            const float bj = bias[c];
            #pragma unroll
            for (int r = 0; r < 4; ++r) {
                const int m = rowb + i * 16 + r;
                float v = acc[i][j][r] + bj;
                if (OP == OP_GELU) v = gelu_tanh(v);
                if (OP == OP_RES)  v += res[(size_t)m * N + c];
                if (WF32) Cf[(size_t)m * N + c] = v;
                if (WB16) Cb[(size_t)m * N + c] = (bf16)v;
            }
        }
    }
}

// ---------------------------------------------------------------------------
// All 9 weight transposes (fp32 KxN -> bf16 NxK) in ONE launch.
// ---------------------------------------------------------------------------
struct TDesc { const float* src; bf16* dst; int K; int N; int tile0; };
struct TDescs { TDesc d[9]; };

__global__ __launch_bounds__(256) void transpose_all(TDescs td)
{
    __shared__ float t[32][33];
    const int blk = blockIdx.x;
    int i = 0;
    #pragma unroll
    for (int j = 1; j < 9; ++j) if (blk >= td.d[j].tile0) i = j;
    const float* src = td.d[i].src;
    bf16* dst = td.d[i].dst;
    const int K = td.d[i].K, N = td.d[i].N;
    const int local = blk - td.d[i].tile0;
    const int ntx = N >> 5;
    const int bx = local % ntx, by = local / ntx;
    const int x = threadIdx.x & 31, y = threadIdx.x >> 5;
    #pragma unroll
    for (int p = 0; p < 32; p += 8)
        t[y + p][x] = src[(size_t)(by * 32 + y + p) * N + bx * 32 + x];
    __syncthreads();
    #pragma unroll
    for (int p = 0; p < 32; p += 8)
        dst[(size_t)(bx * 32 + y + p) * K + by * 32 + x] = (bf16)t[x][y + p];
}

// ---------------------------------------------------------------------------
// Fused preprocessing: one launch replaces {kv_kernel, cvt_kernel,
// rope_tab_kernel, 2x hipMemcpyAsync(bkv)}. All jobs are independent
// elementwise work partitioned by blockIdx range (branch is block-uniform).
// ---------------------------------------------------------------------------
#define PREP_NKV   16384   // MK*EMB/256
#define PREP_NCVT  10976   // MQ*DQ/4/256
#define PREP_NTAB  8
#define PREP_NBKV  4
#define PREP_TOTAL (PREP_NKV + PREP_NCVT + PREP_NTAB + PREP_NBKV)

__global__ __launch_bounds__(256) void prep_kernel(
    const float* __restrict__ x, const float* __restrict__ Wm,
    const float* __restrict__ bm, bf16* __restrict__ kv,
    const float* __restrict__ slow, bf16* __restrict__ slow_b,
    const float* __restrict__ bk, const float* __restrict__ bv,
    float* __restrict__ bkv, float2* __restrict__ tab)
{
    const int blk = blockIdx.x;
    if (blk < PREP_NKV) {
        int idx = blk * 256 + threadIdx.x;
        int r = idx >> 10, n = idx & 1023;
        float4 xv = *(const float4*)(x + (size_t)r * 4);
        float v = bm[n] + xv.x * Wm[n] + xv.y * Wm[1024 + n]
                        + xv.z * Wm[2048 + n] + xv.w * Wm[3072 + n];
        kv[idx] = (bf16)v;
    } else if (blk < PREP_NKV + PREP_NCVT) {
        int i = (blk - PREP_NKV) * 256 + threadIdx.x;
        float4 v = ((const float4*)slow)[i];
        slow_b[4 * i + 0] = (bf16)v.x;
        slow_b[4 * i + 1] = (bf16)v.y;
        slow_b[4 * i + 2] = (bf16)v.z;
        slow_b[4 * i + 3] = (bf16)v.w;
    } else if (blk < PREP_NKV + PREP_NCVT + PREP_NTAB) {
        int i = (blk - PREP_NKV - PREP_NCVT) * 256 + threadIdx.x;
        int f = i >> 5, pos = i & 31;
        float ang = (float)pos * exp2f(-(float)f * 0.20762050593045954f);
        tab[i] = make_float2(cosf(ang), sinf(ang));
    } else {
        int i = (blk - PREP_NKV - PREP_NCVT - PREP_NTAB) * 256 + threadIdx.x;
        bkv[i] = (i < 512) ? bk[i] : bv[i - 512];
    }
}

// ---------------------------------------------------------------------------
// Fused RoPE(q) + RoPE(k) + V transpose: one launch replaces 3.
// Blocks [0,6272): rope q; [6272,8320): rope k; [8320,8832): vt tiles.
// ---------------------------------------------------------------------------
__global__ __launch_bounds__(256) void rope_vt_kernel(
    const bf16* __restrict__ q16, bf16* __restrict__ qbt,
    const bf16* __restrict__ kv16, bf16* __restrict__ kbt,
    const float2* __restrict__ tab, bf16* __restrict__ vt)
{
    __shared__ bf16 t[64][72];
    const int blk = blockIdx.x;
    if (blk < 8320) {
        const bool isq = blk < 6272;
        const int idx = (isq ? blk : blk - 6272) * 256 + threadIdx.x;
        const bf16* in = isq ? q16 : kv16;
        bf16* out = isq ? qbt : kbt;
        const int tok  = isq ? ROWS_Q : ROWS_K;
        const int gdiv = isq ? 196 : 64;
        const int wdiv = isq ? 14 : 8;
        const float sc = isq ? 0.08838834764831843f : 1.0f;
        const int istr = isq ? 512 : 1024;
        int row = idx >> 7;
        int r2 = idx & 127;
        int h = r2 >> 5;
        int j2 = r2 & 31;
        int j = 2 * j2;
        int n = row % tok;
        int tt = n / gdiv;
        int g = n % gdiv;
        int gh = g / wdiv;
        int gw = g % wdiv;
        int j1 = j + 1;
        int pa_i = (j < 22)  ? tt : (j < 43)  ? gh : gw;
        int pb_i = (j1 < 22) ? tt : (j1 < 43) ? gh : gw;
        float2 ta = tab[j * 32 + pa_i];
        float2 tb = tab[j1 * 32 + pb_i];
        size_t ibase = (size_t)row * istr + (size_t)h * 128 + j;
        size_t obase = (size_t)row * 512 + (size_t)h * 128 + j;
        union { u32 w; bf16 e[2]; } ua, ub;
        ua.w = *(const u32*)(in + ibase);
        ub.w = *(const u32*)(in + ibase + 64);
        float x1a = (float)ua.e[0], x1b = (float)ua.e[1];
        float x2a = (float)ub.e[0], x2b = (float)ub.e[1];
        *(u32*)(out + obase)      = pack_bf16((x1a * ta.x - x2a * ta.y) * sc,
                                              (x1b * tb.x - x2b * tb.y) * sc);
        *(u32*)(out + obase + 64) = pack_bf16((x2a * ta.x + x1a * ta.y) * sc,
                                              (x2b * tb.x + x1b * tb.y) * sc);
    } else {
        const int blk2 = blk - 8320;
        const int tt = (blk2 & 31) * 64;
        const int d0 = ((blk2 >> 5) & 1) * 64;
        const int bh = blk2 >> 6;
        const int b = bh >> 2, h = bh & 3;
        const int rr = threadIdx.x >> 4;
        const int cc = (threadIdx.x & 15) * 4;
        #pragma unroll
        for (int p = 0; p < 4; ++p) {
            int r = rr + p * 16;
            *(bf16x4*)&t[r][cc] = *(const bf16x4*)
                (kv16 + (size_t)(b * ROWS_K + tt + r) * 1024 + 512 + h * 128 + d0 + cc);
        }
        __syncthreads();
        #pragma unroll
        for (int p = 0; p < 4; ++p) {
            int r = rr + p * 16;   // d-local
            bf16x4 v;
            v[0] = t[cc + 0][r]; v[1] = t[cc + 1][r];
            v[2] = t[cc + 2][r]; v[3] = t[cc + 3][r];
            *(bf16x4*)(vt + (size_t)bh * HD * ROWS_K + (size_t)(d0 + r) * ROWS_K + tt + cc) = v;
        }
    }
}

// LayerNorm in-place on (rows x 512) + bf16 copy.
__global__ __launch_bounds__(256) void ln_kernel(
    float* __restrict__ xb, const float* __restrict__ g,
    const float* __restrict__ be, bf16* __restrict__ out16)
{
    int wave = threadIdx.x >> 6, lane = threadIdx.x & 63;
    size_t row = (size_t)blockIdx.x * 4 + wave;
    float* xp = xb + row * 512;
    float4 a = ((const float4*)xp)[lane];
    float4 b = ((const float4*)xp)[lane + 64];
    float s  = a.x + a.y + a.z + a.w + b.x + b.y + b.z + b.w;
    float sq = a.x*a.x + a.y*a.y + a.z*a.z + a.w*a.w
             + b.x*b.x + b.y*b.y + b.z*b.z + b.w*b.w;
    #pragma unroll
    for (int off = 32; off; off >>= 1) {
        s  += __shfl_xor(s, off);
        sq += __shfl_xor(sq, off);
    }
    float mean = s * (1.0f / 512.0f);
    float var  = sq * (1.0f / 512.0f) - mean * mean;
    float rstd = rsqrtf(var + 1e-5f);
    float4 gv1 = ((const float4*)g)[lane],  gv2 = ((const float4*)g)[lane + 64];
    float4 bv1 = ((const float4*)be)[lane], bv2 = ((const float4*)be)[lane + 64];
    a.x = (a.x - mean) * rstd * gv1.x + bv1.x;
    a.y = (a.y - mean) * rstd * gv1.y + bv1.y;
    a.z = (a.z - mean) * rstd * gv1.z + bv1.z;
    a.w = (a.w - mean) * rstd * gv1.w + bv1.w;
    b.x = (b.x - mean) * rstd * gv2.x + bv2.x;
    b.y = (b.y - mean) * rstd * gv2.y + bv2.y;
    b.z = (b.z - mean) * rstd * gv2.z + bv2.z;
    b.w = (b.w - mean) * rstd * gv2.w + bv2.w;
    ((float4*)xp)[lane]      = a;
    ((float4*)xp)[lane + 64] = b;
    bf16* op = out16 + row * 512;
    *(u32*)(op + lane * 4)       = pack_bf16(a.x, a.y);
    *(u32*)(op + lane * 4 + 2)   = pack_bf16(a.z, a.w);
    *(u32*)(op + 256 + lane * 4)     = pack_bf16(b.x, b.y);
    *(u32*)(op + 256 + lane * 4 + 2) = pack_bf16(b.z, b.w);
}

// ---------------------------------------------------------------------------
// MFMA flash attention — FROZEN at the R7 configuration (verbatim round-0
// body, strides 136/72/136, XCD swizzle). R6/R7 established: structure-bound
// at ~121us; grid/split/traffic changes neutral; per-wave restructures break
// regalloc (rounds 1-4); padded strides were a 3x LDS-misalignment trap (R5).
// ---------------------------------------------------------------------------
__global__ __launch_bounds__(256, 2) void mattn_kernel(
    const bf16* __restrict__ qs, const bf16* __restrict__ ks,
    const bf16* __restrict__ vt, bf16* __restrict__ outb)
{
    __shared__ __align__(16) char smem[35840];
    bf16* Ksh = (bf16*)smem;            // [64][136]
    bf16* Vsh = (bf16*)(smem + 17408);  // [128][72]

    const int tid = threadIdx.x;
    const int wave = tid >> 6, lane = tid & 63;
    const int quad = lane >> 4, c = lane & 15;
    const int bid = blockIdx.x;
    const int bh = bid & 7;             // XCD-locality: same (b,h) -> same XCD
    const int qt = bid >> 3;
    const int h  = bh & 3;
    const int b  = bh >> 2;

    const int q0 = qt * 128 + wave * 32;
    const bf16* qg = qs + (size_t)(b * ROWS_Q + q0) * HID + h * HD;
    const bf16* kg = ks + (size_t)(b * ROWS_K) * HID + h * HD;
    const bf16* vg = vt + (size_t)(b * NH + h) * HD * ROWS_K;

    bf16x8 qf[2][4];
    #pragma unroll
    for (int n = 0; n < 2; ++n)
        #pragma unroll
        for (int s = 0; s < 4; ++s)
            qf[n][s] = *(const bf16x8*)(qg + (size_t)(n * 16 + c) * HID + s * 32 + quad * 8);

    f32x4 o[8][2] = {};
    float m_i[2] = {-1e30f, -1e30f}, l_i[2] = {0.0f, 0.0f};

    const int st_t = tid >> 2;
    const int st_d = (tid & 3) * 32;
    const int sv_d = tid >> 1;
    const int sv_t = (tid & 1) * 32;

    for (int kt = 0; kt < 32; ++kt) {
        __syncthreads();
        {
            const bf16* src = kg + (size_t)(kt * 64 + st_t) * HID + st_d;
            bf16* dst = Ksh + st_t * 136 + st_d;
            #pragma unroll
            for (int i = 0; i < 4; ++i)
                *(bf16x8*)(dst + i * 8) = *(const bf16x8*)(src + i * 8);
        }
        {
            const bf16* src = vg + (size_t)sv_d * ROWS_K + kt * 64 + sv_t;
            bf16* dst = Vsh + sv_d * 72 + sv_t;
            #pragma unroll
            for (int i = 0; i < 4; ++i)
                *(bf16x8*)(dst + i * 8) = *(const bf16x8*)(src + i * 8);
        }
        __syncthreads();

        f32x4 s[4][2] = {};
        #pragma unroll
        for (int ksi = 0; ksi < 4; ++ksi) {
            bf16x8 kf[4];
            #pragma unroll
            for (int mi = 0; mi < 4; ++mi)
                kf[mi] = *(const bf16x8*)(Ksh + (mi * 16 + c) * 136 + ksi * 32 + quad * 8);
            #pragma unroll
            for (int mi = 0; mi < 4; ++mi)
                #pragma unroll
                for (int n = 0; n < 2; ++n)
                    s[mi][n] = __builtin_amdgcn_mfma_f32_16x16x32_bf16(
                        kf[mi], qf[n][ksi], s[mi][n], 0, 0, 0);
        }

        float alpha[2];
        #pragma unroll
        for (int n = 0; n < 2; ++n) {
            float mx = -1e30f;
            #pragma unroll
            for (int mi = 0; mi < 4; ++mi)
                #pragma unroll
                for (int r = 0; r < 4; ++r) mx = fmaxf(mx, s[mi][n][r]);
            mx = fmaxf(mx, __shfl_xor(mx, 16));
            mx = fmaxf(mx, __shfl_xor(mx, 32));
            float mn = fmaxf(m_i[n], mx);
            alpha[n] = __expf(m_i[n] - mn);
            m_i[n] = mn;
            float sm = 0.0f;
            #pragma unroll
            for (int mi = 0; mi < 4; ++mi)
                #pragma unroll
                for (int r = 0; r < 4; ++r) {
                    float p = __expf(s[mi][n][r] - mn);
                    s[mi][n][r] = p;
                    sm += p;
                }
            sm += __shfl_xor(sm, 16);
            sm += __shfl_xor(sm, 32);
            l_i[n] = l_i[n] * alpha[n] + sm;
            #pragma unroll
            for (int md = 0; md < 8; ++md) {
                o[md][n][0] *= alpha[n]; o[md][n][1] *= alpha[n];
                o[md][n][2] *= alpha[n]; o[md][n][3] *= alpha[n];
            }
        }

        u32 pk[4][2][2];
        #pragma unroll
        for (int mi = 0; mi < 4; ++mi)
            #pragma unroll
            for (int n = 0; n < 2; ++n) {
                pk[mi][n][0] = pack_bf16(s[mi][n][0], s[mi][n][1]);
                pk[mi][n][1] = pack_bf16(s[mi][n][2], s[mi][n][3]);
            }
        bf16x8 pf[2][2];
        #pragma unroll
        for (int kst = 0; kst < 2; ++kst)
            #pragma unroll
            for (int n = 0; n < 2; ++n) {
                union { bf16x8 v8; u32 d[4]; } u;
                #pragma unroll
                for (int dw = 0; dw < 4; ++dw) {
                    int srcl = ((quad & 1) * 2 + (dw >> 1)) * 16 + c;
                    u32 lo = (u32)__shfl((int)pk[2 * kst][n][dw & 1], srcl);
                    u32 hi = (u32)__shfl((int)pk[2 * kst + 1][n][dw & 1], srcl);
                    u.d[dw] = (quad >= 2) ? hi : lo;
                }
                pf[kst][n] = u.v8;
            }

        #pragma unroll
        for (int kst = 0; kst < 2; ++kst)
            #pragma unroll
            for (int md = 0; md < 8; ++md) {
                bf16x8 vf = *(const bf16x8*)(Vsh + (md * 16 + c) * 72 + kst * 32 + quad * 8);
                #pragma unroll
                for (int n = 0; n < 2; ++n)
                    o[md][n] = __builtin_amdgcn_mfma_f32_16x16x32_bf16(
                        vf, pf[kst][n], o[md][n], 0, 0, 0);
            }
    }

    __syncthreads();
    bf16* Osh = (bf16*)smem + wave * (32 * 136);
    float inv[2] = {1.0f / l_i[0], 1.0f / l_i[1]};
    #pragma unroll
    for (int md = 0; md < 8; ++md)
        #pragma unroll
        for (int n = 0; n < 2; ++n)
            #pragma unroll
            for (int hh = 0; hh < 2; ++hh) {
                u32 w = pack_bf16(o[md][n][2 * hh] * inv[n], o[md][n][2 * hh + 1] * inv[n]);
                int d = md * 16 + quad * 4 + 2 * hh;
                int qq = n * 16 + c;
                *(u32*)(Osh + qq * 136 + d) = w;
            }
    __syncthreads();
    bf16* og = outb + (size_t)(b * ROWS_Q + q0) * HID + h * HD;
    #pragma unroll
    for (int i = 0; i < 8; ++i) {
        int idx = i * 64 + lane;
        int qq = idx >> 4;
        int ch = idx & 15;
        bf16x8 vv = *(const bf16x8*)(Osh + qq * 136 + ch * 8);
        *(bf16x8*)(og + (size_t)qq * HID + ch * 8) = vv;
    }
}

extern "C" void kernel_launch(void* const* d_in, const int* in_sizes, int n_in,
                              void* d_out, int out_size, void* d_ws, size_t ws_size,
                              hipStream_t stream)
{
    const float* x     = (const float*)d_in[0];
    const float* slow  = (const float*)d_in[1];
    const float* Wq_in = (const float*)d_in[3];
    const float* bq_in = (const float*)d_in[4];
    const float* Wm    = (const float*)d_in[5];
    const float* bm    = (const float*)d_in[6];
    const float* Wq    = (const float*)d_in[7];
    const float* bq    = (const float*)d_in[8];
    const float* Wk    = (const float*)d_in[9];
    const float* bk    = (const float*)d_in[10];
    const float* Wv    = (const float*)d_in[11];
    const float* bv    = (const float*)d_in[12];
    const float* Wo    = (const float*)d_in[13];
    const float* bo    = (const float*)d_in[14];
    const float* g1    = (const float*)d_in[15];
    const float* be1   = (const float*)d_in[16];
    const float* W1    = (const float*)d_in[17];
    const float* b1    = (const float*)d_in[18];
    const float* W2    = (const float*)d_in[19];
    const float* b2    = (const float*)d_in[20];
    const float* g2    = (const float*)d_in[21];
    const float* be2   = (const float*)d_in[22];
    const float* M1    = (const float*)d_in[23];
    const float* bm1   = (const float*)d_in[24];
    const float* M2    = (const float*)d_in[25];
    const float* bm2   = (const float*)d_in[26];
    float* out = (float*)d_out;

    // ---- workspace layout ----
    float* q_in_f = (float*)d_ws;                         // MQ*512 f32
    float* ob     = q_in_f + (size_t)MQ * HID;            // MQ*512 f32
    float* bkv    = ob + (size_t)MQ * HID;                // 1024 f32
    bf16* shared_b = (bf16*)(bkv + 1024);                 // MQ*1024 (slow_b/attn_b/ff1_b/m1_b)
    bf16* q_in_b = shared_b + (size_t)MQ * FF;            // MQ*512
    bf16* kv_b   = q_in_b + (size_t)MQ * HID;             // MK*1024
    bf16* h_b    = kv_b + (size_t)MK * EMB;               // MQ*512
    bf16* q16    = h_b + (size_t)MQ * HID;                // MQ*512
    bf16* kv16   = q16 + (size_t)MQ * HID;                // MK*1024 (k|v fused)
    bf16* qbt    = kv16 + (size_t)MK * EMB;               // MQ*512
    bf16* kbt    = qbt + (size_t)MQ * HID;                // MK*512
    bf16* Vt     = kbt + (size_t)MK * HID;                // 8*128*2048
    bf16* Wq_in_t = Vt + (size_t)8 * HD * ROWS_K;         // 512*896
    bf16* Wq_t  = Wq_in_t + 512 * 896;                    // 512*512
    bf16* kvw_t = Wq_t + 512 * 512;                       // 1024*1024 (Wk_t | Wv_t)
    bf16* Wo_t  = kvw_t + 1024 * 1024;                    // 512*512
    bf16* W1_t  = Wo_t + 512 * 512;                       // 1024*512
    bf16* W2_t  = W1_t + 1024 * 512;                      // 512*1024
    bf16* M1_t  = W2_t + 512 * 1024;                      // 1024*512
    bf16* M2_t  = M1_t + 1024 * 512;                      // 896*1024
    bf16* slow_b = shared_b;
    bf16* attn_b = shared_b;
    bf16* ff1_b  = shared_b;
    bf16* m1_b   = shared_b;

    // RoPE cos/sin table: lives in ob (dead until the Wo GEMM, long after rope)
    float2* rtab = (float2*)ob;                           // 64*32 float2 = 16 KB

    dim3 blk(256);

    // ---- all weight transposes in one launch ----
    TDescs td;
    int t0 = 0;
    auto set = [&](int i, const float* s, bf16* d, int K, int N) {
        td.d[i] = {s, d, K, N, t0};
        t0 += (N / 32) * (K / 32);
    };
    set(0, Wq_in, Wq_in_t, 896, 512);
    set(1, Wq,    Wq_t,    512, 512);
    set(2, Wk,    kvw_t,              1024, 512);
    set(3, Wv,    kvw_t + 512 * 1024, 1024, 512);
    set(4, Wo,    Wo_t,    512, 512);
    set(5, W1,    W1_t,    512, 1024);
    set(6, W2,    W2_t,    1024, 512);
    set(7, M1,    M1_t,    512, 1024);
    set(8, M2,    M2_t,    1024, 896);
    transpose_all<<<t0, blk, 0, stream>>>(td);

    // fused preprocessing: kv proj + slow cvt + rope table + bias concat
    prep_kernel<<<PREP_TOTAL, blk, 0, stream>>>(
        x, Wm, bm, kv_b, slow, slow_b, bk, bv, bkv, rtab);

    // q_in = slow @ Wq_in + bq_in -> fp32 (residual) + bf16   grid 4x196
    mgemm64<OP_BIAS, true, true><<<dim3(4, 196), blk, 0, stream>>>(
        slow_b, Wq_in_t, bq_in, nullptr, q_in_f, q_in_b, MQ, HID, DQ);
    // q projection -> bf16   grid 4x196
    mgemm64<OP_BIAS, false, true><<<dim3(4, 196), blk, 0, stream>>>(
        q_in_b, Wq_t, bq, nullptr, nullptr, q16, MQ, HID, HID);
    // fused k|v projection -> kv16 (MK x 1024)   grid 8x64
    mgemm64<OP_BIAS, false, true><<<dim3(8, 64), blk, 0, stream>>>(
        kv_b, kvw_t, bkv, nullptr, nullptr, kv16, MK, 1024, EMB);
    // fused RoPE(q) + RoPE(k) + V transpose
    rope_vt_kernel<<<dim3(8832), blk, 0, stream>>>(q16, qbt, kv16, kbt, rtab, Vt);
    // MFMA flash attention -> attn_b (bf16), grid 392, XCD-swizzled
    mattn_kernel<<<dim3(392), blk, 0, stream>>>(qbt, kbt, Vt, attn_b);
    // pre_ln = attn @ Wo + bo + q_in   grid 4x196
    mgemm64<OP_RES, true, false><<<dim3(4, 196), blk, 0, stream>>>(
        attn_b, Wo_t, bo, q_in_f, ob, nullptr, MQ, HID, HID);
    ln_kernel<<<MQ / 4, blk, 0, stream>>>(ob, g1, be1, h_b);
    // ff1 = gelu(h @ W1 + b1)   grid 8x98 (128-tile, 32x32 MFMA)
    mgemm<OP_GELU, false, true><<<dim3(8, 98), blk, 0, stream>>>(
        h_b, W1_t, b1, nullptr, nullptr, ff1_b, MQ, FF, HID);
    // pre2 = ff1 @ W2 + b2 + h   grid 4x196
    mgemm64<OP_RES, true, false><<<dim3(4, 196), blk, 0, stream>>>(
        ff1_b, W2_t, b2, ob, q_in_f, nullptr, MQ, HID, FF);
    ln_kernel<<<MQ / 4, blk, 0, stream>>>(q_in_f, g2, be2, h_b);
    // m1 = gelu(h2 @ M1 + bm1)   grid 8x98 (32x32 MFMA)
    mgemm<OP_GELU, false, true><<<dim3(8, 98), blk, 0, stream>>>(
        h_b, M1_t, bm1, nullptr, nullptr, m1_b, MQ, 2 * HID, HID);
    // out = m1 @ M2 + bm2   grid 7x98 (32x32 MFMA)
    mgemm<OP_BIAS, true, false><<<dim3(7, 98), blk, 0, stream>>>(
        m1_b, M2_t, bm2, nullptr, out, nullptr, MQ, OUTD, 2 * HID);
}